// Round 5
// baseline (417.349 us; speedup 1.0000x reference)
//
#include <hip/hip_runtime.h>
#include <math.h>

typedef __attribute__((ext_vector_type(8))) short short8;
typedef __attribute__((ext_vector_type(4))) float f32x4;
typedef __attribute__((ext_vector_type(4))) unsigned short u16x4;

#define EPSV 1e-7f
#define PI_2 1.57079632679489662f
#define NEG_BIG (-3.4e38f)

constexpr int B = 4, C = 256;
constexpr int GW = 50;
constexpr int PR = 2500, PP = 2560;              // real / padded 50x50
constexpr int CPP = C * PP;                      // 655,360
constexpr long long SPB = (long long)PP * PP;    // 6,553,600
constexpr int PS = PP * C;                       // partial slice
constexpr int ZT = 213176;                       // sum_l B*H_l*W_l

// ---- workspace float offsets ----
constexpr size_t OFF_ORI   = 0;                            // fp32 [4][256][2560]
constexpr size_t OFF_BSF   = OFF_ORI + (size_t)B * CPP;
constexpr size_t OFF_Z     = OFF_BSF + (size_t)B * CPP;    // fp32 [9][ZT]
constexpr size_t OFF_BASIC = OFF_Z + (size_t)9 * ZT;
constexpr size_t OFF_ROW   = OFF_BASIC + 213184;
constexpr size_t OFF_COL   = OFF_ROW + 1600;
constexpr size_t OFF_STATS = OFF_COL + 1600;
constexpr size_t OFF_U16   = OFF_STATS + 128;
// ---- u16 offsets within u16 region ----
constexpr size_t U_ORIT = 0;                               // [4][2560][256]
constexpr size_t U_THT  = U_ORIT + (size_t)B * CPP;        // [4][2560][256]
constexpr size_t U_PHT  = U_THT  + (size_t)B * CPP;        // [4][2560][256]
constexpr size_t U_G    = U_PHT  + (size_t)B * CPP;        // [4][256][2560]
constexpr size_t U_YTT  = U_G    + (size_t)B * CPP;        // [4][2560][256]
constexpr size_t U_WB   = U_YTT  + (size_t)B * CPP;        // 4 x [256][256] th,ph,g,out

__device__ __forceinline__ unsigned short f2b(float x) {
    union { float f; unsigned u; } q{x};
    unsigned r = q.u + 0x7FFFu + ((q.u >> 16) & 1u);
    return (unsigned short)(r >> 16);
}
__device__ __forceinline__ float b2f(unsigned short u) {
    union { unsigned u; float f; } q{(unsigned)u << 16};
    return q.f;
}

// ================= k_pre: wcvt | orife | rowmean | colmean =================
// block ranges: [0,1024) wcvt, [1024,11264) orife, [11264,11652) rowm, [11652,11659) colm
__global__ __launch_bounds__(256) void k_pre(
    const float* __restrict__ x0, const float* __restrict__ x1,
    const float* __restrict__ x2, const float* __restrict__ x3,
    const float* __restrict__ x4,
    const float* __restrict__ wth, const float* __restrict__ wph,
    const float* __restrict__ wg,  const float* __restrict__ wout,
    unsigned short* __restrict__ wb, float* __restrict__ ori,
    float* __restrict__ row, float* __restrict__ col)
{
    const int bx = blockIdx.x;
    const int tid = threadIdx.x;

    if (bx < 1024) {
        // ---- weight convert: 4 x 256x256 ----
        int idx = bx * 256 + tid;
        int seg = idx >> 16, off = idx & 65535;
        const float* s = (seg == 0) ? wth : (seg == 1) ? wph : (seg == 2) ? wg : wout;
        wb[idx] = f2b(s[off]);
    } else if (bx < 11264) {
        // ---- ori_fe gather (padded, pads = 0) ----
        int idx = (bx - 1024) * 256 + tid;
        int p = idx % PP; int bc = idx / PP;
        float v = 0.0f;
        if (p < PR) {
            int y = p / GW, x = p % GW;
            const float* p0 = x0 + (size_t)bc * 40000;
            float m0 = NEG_BIG;
            #pragma unroll
            for (int dy = 0; dy < 4; dy++) {
                f32x4 r = *(const f32x4*)(p0 + (y * 4 + dy) * 200 + x * 4);
                m0 = fmaxf(m0, fmaxf(fmaxf(r[0], r[1]), fmaxf(r[2], r[3])));
            }
            const float* p1 = x1 + (size_t)bc * 10000;
            float m1 = fmaxf(fmaxf(p1[(y*2)*100 + x*2],   p1[(y*2)*100 + x*2+1]),
                             fmaxf(p1[(y*2+1)*100 + x*2], p1[(y*2+1)*100 + x*2+1]));
            float v2 = x2[(size_t)bc * 2500 + p];
            float v3 = x3[(size_t)bc * 625 + (y/2)*25 + (x/2)];
            int ry = (y * 13) / 50, rx = (x * 13) / 50;
            float v4 = x4[(size_t)bc * 169 + ry * 13 + rx];
            v = (m0 + m1 + v2 + v3 + v4) * 0.2f;
        }
        ori[idx] = v;
    } else if (bx < 11652) {
        // ---- row means: 4 rows/block, one per wave ----
        int rid = (bx - 11264) * 4 + (tid >> 6);
        int lane = tid & 63;
        int base, H; const float* x;
        if      (rid < 800)  { base = 0;    H = 200; x = x0; }
        else if (rid < 1200) { base = 800;  H = 100; x = x1; }
        else if (rid < 1400) { base = 1200; H = 50;  x = x2; }
        else if (rid < 1500) { base = 1400; H = 25;  x = x3; }
        else                 { base = 1500; H = 13;  x = x4; }
        int r = rid - base; int b = r / H, h = r - (r / H) * H;
        const float* xr = x + (size_t)b * C * H * H + (size_t)h * H;
        float s = 0.0f;
        for (int w = lane; w < H; w += 64) s += xr[w];
        #pragma unroll
        for (int off = 32; off > 0; off >>= 1) s += __shfl_down(s, off);
        if (lane == 0) row[rid] = s / (float)H;
    } else {
        // ---- col means: thread per (lvl,b,w) ----
        int idx = (bx - 11652) * 256 + tid;
        if (idx >= 1552) return;
        int base, H; const float* x;
        if      (idx < 800)  { base = 0;    H = 200; x = x0; }
        else if (idx < 1200) { base = 800;  H = 100; x = x1; }
        else if (idx < 1400) { base = 1200; H = 50;  x = x2; }
        else if (idx < 1500) { base = 1400; H = 25;  x = x3; }
        else                 { base = 1500; H = 13;  x = x4; }
        int r = idx - base; int b = r / H, w = r - (r / H) * H;
        const float* xc = x + (size_t)b * C * H * H + w;
        float s = 0.0f;
        for (int h = 0; h < H; h++) s += xc[(size_t)h * H];
        col[idx] = s / (float)H;
    }
}

// ================= conv3x3 pass1: 1 px/thread, 256 channels, no barriers =================
// z[tap][zb + b*HW + p] = sum_c w[c][tap] * x[b][c][p]
__global__ __launch_bounds__(256) void k_ctap(
    const float* __restrict__ x0, const float* __restrict__ x1,
    const float* __restrict__ x2, const float* __restrict__ x3,
    const float* __restrict__ x4, const float* __restrict__ rc_w,
    float* __restrict__ z)
{
    __shared__ float wsm[C * 12];
    const int bx = blockIdx.x;
    const int tid = threadIdx.x;

    int lvl, base, HW, zb; const float* x;
    if      (bx < 625) { lvl = 0; base = 0;   HW = 40000; zb = 0;      x = x0; }
    else if (bx < 782) { lvl = 1; base = 625; HW = 10000; zb = 160000; x = x1; }
    else if (bx < 822) { lvl = 2; base = 782; HW = 2500;  zb = 200000; x = x2; }
    else if (bx < 832) { lvl = 3; base = 822; HW = 625;   zb = 210000; x = x3; }
    else               { lvl = 4; base = 832; HW = 169;   zb = 212500; x = x4; }

    const float* w9 = rc_w + (size_t)lvl * C * 9;
    for (int i = tid; i < C * 9; i += 256) wsm[(i / 9) * 12 + (i % 9)] = w9[i];
    __syncthreads();

    int idx = (bx - base) * 256 + tid;          // over B*HW for this level
    if (idx >= B * HW) return;
    int b = idx / HW, p = idx - b * HW;

    float acc[9] = {};
    const float* xp = x + (size_t)b * C * HW + p;
    #pragma unroll 4
    for (int c = 0; c < C; c++) {
        float v = xp[(size_t)c * HW];
        const float* wc = &wsm[c * 12];
        f32x4 w0 = *(const f32x4*)wc;
        f32x4 w1 = *(const f32x4*)(wc + 4);
        float w8 = wc[8];
        acc[0] += v * w0[0]; acc[1] += v * w0[1]; acc[2] += v * w0[2]; acc[3] += v * w0[3];
        acc[4] += v * w1[0]; acc[5] += v * w1[1]; acc[6] += v * w1[2]; acc[7] += v * w1[3];
        acc[8] += v * w8;
    }
    #pragma unroll
    for (int t = 0; t < 9; t++)
        z[(size_t)t * ZT + zb + idx] = acc[t];
}

// ================= transpose+convert: ori fp32 [b][c][p] -> u16 [b][p][c] =================
__global__ __launch_bounds__(256) void k_tcvt(const float* __restrict__ ori,
                                              unsigned short* __restrict__ ot)
{
    __shared__ unsigned short t[64][66];
    int p0 = blockIdx.x * 64, c0 = blockIdx.y * 64, b = blockIdx.z;
    int pp = threadIdx.x & 63, cb = threadIdx.x >> 6;
    #pragma unroll
    for (int i = 0; i < 16; i++) {
        int cc = cb * 16 + i;
        t[cc][pp] = f2b(ori[((size_t)b * C + c0 + cc) * PP + p0 + pp]);
    }
    __syncthreads();
    int cc2 = threadIdx.x & 63, pb = threadIdx.x >> 6;
    #pragma unroll
    for (int i = 0; i < 16; i++) {
        int pp2 = pb * 16 + i;
        ot[((size_t)b * PP + p0 + pp2) * C + c0 + cc2] = t[cc2][pp2];
    }
}

// ================= merged projections (th, ph, g) =================
constexpr int LDT = 40;

__global__ __launch_bounds__(256) void k_proj(
    const unsigned short* __restrict__ wb, const unsigned short* __restrict__ orit,
    const float* __restrict__ th_b, const float* __restrict__ ph_b,
    const float* __restrict__ g_b,
    unsigned short* __restrict__ tht, unsigned short* __restrict__ pht,
    unsigned short* __restrict__ gb)
{
    __shared__ __align__(16) unsigned short As[128 * LDT];
    __shared__ __align__(16) unsigned short Bs[128 * LDT];

    const int z = blockIdx.z;
    const int b = z / 3, wsel = z - b * 3;
    const bool tp = (wsel < 2);
    const unsigned short* A = tp ? (orit + (size_t)b * CPP) : (wb + 131072);
    const unsigned short* Bm = tp ? (wb + wsel * 65536) : (orit + (size_t)b * CPP);
    const float* bias = (wsel == 0) ? th_b : (wsel == 1) ? ph_b : g_b;

    const int m0 = (tp ? blockIdx.x : blockIdx.y) * 128;
    const int n0 = (tp ? blockIdx.y : blockIdx.x) * 128;
    const int tid = threadIdx.x;
    const int lane = tid & 63, w = tid >> 6;
    const int wm = (w & 1) * 64, wn = (w >> 1) * 64;
    const int fr = lane & 15, fq = lane >> 4;

    f32x4 acc[4][4] = {};
    for (int k0 = 0; k0 < 256; k0 += 32) {
        #pragma unroll
        for (int l = 0; l < 2; l++) {
            int li = tid + l * 256;
            int rr = li >> 2, kc = li & 3;
            short8 va = *(const short8*)(A  + (size_t)(m0 + rr) * 256 + k0 + kc * 8);
            short8 vb = *(const short8*)(Bm + (size_t)(n0 + rr) * 256 + k0 + kc * 8);
            *(short8*)&As[rr * LDT + kc * 8] = va;
            *(short8*)&Bs[rr * LDT + kc * 8] = vb;
        }
        __syncthreads();
        short8 af[4], bf[4];
        #pragma unroll
        for (int i = 0; i < 4; i++)
            af[i] = *(const short8*)&As[(wm + i * 16 + fr) * LDT + fq * 8];
        #pragma unroll
        for (int j = 0; j < 4; j++)
            bf[j] = *(const short8*)&Bs[(wn + j * 16 + fr) * LDT + fq * 8];
        #pragma unroll
        for (int i = 0; i < 4; i++)
            #pragma unroll
            for (int j = 0; j < 4; j++)
                acc[i][j] = __builtin_amdgcn_mfma_f32_16x16x32_bf16(
                    af[i], bf[j], acc[i][j], 0, 0, 0);
        __syncthreads();
    }

    unsigned short* dst = (wsel == 0) ? tht : (wsel == 1) ? pht : gb;
    dst += (size_t)b * CPP;
    #pragma unroll
    for (int i = 0; i < 4; i++) {
        #pragma unroll
        for (int r = 0; r < 4; r++) {
            int gm = m0 + wm + i * 16 + fq * 4 + r;
            #pragma unroll
            for (int j = 0; j < 4; j++) {
                int gn = n0 + wn + j * 16 + fr;
                float v = acc[i][j][r] + (tp ? bias[gn] : bias[gm]);
                size_t off = tp ? ((size_t)gm * 256 + gn) : ((size_t)gm * PP + gn);
                dst[off] = f2b(v);
            }
        }
    }
}

// ================= generic bf16 MFMA GEMM: C = A[M][K] * B[N][K]^T =================
template<bool AddBias, bool AddRes, bool OutBf>
__global__ __launch_bounds__(256) void k_bgemm(
    const unsigned short* __restrict__ A, const unsigned short* __restrict__ Bm,
    const float* __restrict__ bias, const float* __restrict__ res,
    void* __restrict__ Cout, int K, int lda, int ldb, int ldc,
    long long sA, long long sB, long long sC, long long sR,
    int nsplit, long long sK)
{
    __shared__ __align__(16) unsigned short As[128 * LDT];
    __shared__ __align__(16) unsigned short Bs[128 * LDT];

    const int z = blockIdx.z;
    const int bz = z / nsplit, ks = z - bz * nsplit;
    A  += (size_t)sA * bz + (size_t)sK * ks;
    Bm += (size_t)sB * bz + (size_t)sK * ks;

    const int m0 = blockIdx.y * 128, n0 = blockIdx.x * 128;
    const int tid = threadIdx.x;
    const int lane = tid & 63, w = tid >> 6;
    const int wm = (w & 1) * 64, wn = (w >> 1) * 64;
    const int fr = lane & 15, fq = lane >> 4;

    f32x4 acc[4][4] = {};
    for (int k0 = 0; k0 < K; k0 += 32) {
        #pragma unroll
        for (int l = 0; l < 2; l++) {
            int li = tid + l * 256;
            int rr = li >> 2, kc = li & 3;
            short8 va = *(const short8*)(A  + (size_t)(m0 + rr) * lda + k0 + kc * 8);
            short8 vb = *(const short8*)(Bm + (size_t)(n0 + rr) * ldb + k0 + kc * 8);
            *(short8*)&As[rr * LDT + kc * 8] = va;
            *(short8*)&Bs[rr * LDT + kc * 8] = vb;
        }
        __syncthreads();
        short8 af[4], bf[4];
        #pragma unroll
        for (int i = 0; i < 4; i++)
            af[i] = *(const short8*)&As[(wm + i * 16 + fr) * LDT + fq * 8];
        #pragma unroll
        for (int j = 0; j < 4; j++)
            bf[j] = *(const short8*)&Bs[(wn + j * 16 + fr) * LDT + fq * 8];
        #pragma unroll
        for (int i = 0; i < 4; i++)
            #pragma unroll
            for (int j = 0; j < 4; j++)
                acc[i][j] = __builtin_amdgcn_mfma_f32_16x16x32_bf16(
                    af[i], bf[j], acc[i][j], 0, 0, 0);
        __syncthreads();
    }

    float* Cf = (float*)Cout;
    unsigned short* Cb = (unsigned short*)Cout;
    const size_t co = (size_t)sC * z;
    const size_t ro = (size_t)sR * bz;
    #pragma unroll
    for (int i = 0; i < 4; i++) {
        #pragma unroll
        for (int r = 0; r < 4; r++) {
            int gm = m0 + wm + i * 16 + fq * 4 + r;
            #pragma unroll
            for (int j = 0; j < 4; j++) {
                int gn = n0 + wn + j * 16 + fr;
                float v = acc[i][j][r];
                if (AddBias) v += bias[gm];
                if (AddRes)  v += res[ro + (size_t)gm * ldc + gn];
                size_t off = co + (size_t)gm * ldc + gn;
                if (OutBf) Cb[off] = f2b(v);
                else       Cf[off] = v;
            }
        }
    }
}

// ================= yt split-K reduce: 4 fp32 partials -> bf16 ytt =================
__global__ __launch_bounds__(256) void k_ytred(const float* __restrict__ part,
                                               unsigned short* __restrict__ ytt)
{
    int idx = blockIdx.x * 256 + threadIdx.x;
    if (idx >= B * CPP / 4) return;
    int b = idx / (CPP / 4);
    int r = idx - b * (CPP / 4);
    const float* p = part + (size_t)(b * 4) * PS + (size_t)r * 4;
    f32x4 s = *(const f32x4*)p;
    #pragma unroll
    for (int ks = 1; ks < 4; ks++) {
        f32x4 q = *(const f32x4*)(p + (size_t)ks * PS);
        s[0] += q[0]; s[1] += q[1]; s[2] += q[2]; s[3] += q[3];
    }
    u16x4 o;
    #pragma unroll
    for (int k = 0; k < 4; k++) o[k] = f2b(s[k]);
    *(u16x4*)(ytt + (size_t)b * CPP + (size_t)r * 4) = o;
}

// ================= row softmax: bf16 S rows -> bf16 P rows =================
__global__ __launch_bounds__(256) void k_softmax(const unsigned short* __restrict__ S,
                                                 unsigned short* __restrict__ P)
{
    __shared__ float red[256];
    const int row = blockIdx.x;
    const unsigned short* r = S + (size_t)row * PP;
    unsigned short* p = P + (size_t)row * PP;
    const int t = threadIdx.x;
    float v[10];
    float mx = NEG_BIG;
    #pragma unroll
    for (int i = 0; i < 10; i++) {
        int j = i * 256 + t;
        v[i] = (j < PR) ? b2f(r[j]) : NEG_BIG;
        mx = fmaxf(mx, v[i]);
    }
    red[t] = mx; __syncthreads();
    for (int s = 128; s > 0; s >>= 1) { if (t < s) red[t] = fmaxf(red[t], red[t+s]); __syncthreads(); }
    mx = red[0]; __syncthreads();
    float sum = 0.0f;
    #pragma unroll
    for (int i = 0; i < 10; i++) { float e = __expf(v[i] - mx); v[i] = e; sum += e; }
    red[t] = sum; __syncthreads();
    for (int s = 128; s > 0; s >>= 1) { if (t < s) red[t] += red[t+s]; __syncthreads(); }
    float inv = 1.0f / red[0];
    #pragma unroll
    for (int i = 0; i < 10; i++) p[i * 256 + t] = f2b(v[i] * inv);
}

// ================= conv3x3 pass2 fused =================
template<int H, int ZB>
__device__ __forceinline__ void ccomb_impl(int idx, const float* __restrict__ z,
                                           float biasv, float* __restrict__ bas)
{
    constexpr int W = H, HW = H * W;
    int r = idx - ZB; int b = r / HW; int p = r - b * HW;
    int y = p / W, x = p - (p / W) * W;
    float acc = biasv;
    #pragma unroll
    for (int dy = 0; dy < 3; dy++) {
        int yy = y + dy - 1;
        if (yy < 0 || yy >= H) continue;
        #pragma unroll
        for (int dx = 0; dx < 3; dx++) {
            int xx = x + dx - 1;
            if (xx < 0 || xx >= W) continue;
            acc += z[(size_t)(dy * 3 + dx) * ZT + ZB + (size_t)b * HW + yy * W + xx];
        }
    }
    bas[idx] = fmaxf(acc, 0.0f);
}

__global__ __launch_bounds__(256) void k_ccomb_f(const float* __restrict__ z,
                                                 const float* __restrict__ rb,
                                                 float* __restrict__ bas)
{
    int idx = blockIdx.x * 256 + threadIdx.x;
    if (idx >= ZT) return;
    if      (idx < 160000) ccomb_impl<200, 0>     (idx, z, rb[0], bas);
    else if (idx < 200000) ccomb_impl<100, 160000>(idx, z, rb[1], bas);
    else if (idx < 210000) ccomb_impl<50,  200000>(idx, z, rb[2], bas);
    else if (idx < 212500) ccomb_impl<25,  210000>(idx, z, rb[3], bas);
    else                   ccomb_impl<13,  212500>(idx, z, rb[4], bas);
}

// ================= per-sample stats fused (block per (lvl,b)) =================
__global__ __launch_bounds__(256) void k_stats_f(
    const float* __restrict__ row, const float* __restrict__ col,
    const float* __restrict__ basic, float* __restrict__ stats)
{
    const int Ht[5]  = {200, 100, 50, 25, 13};
    const int ZBt[5] = {0, 160000, 200000, 210000, 212500};
    const int RBt[5] = {0, 800, 1200, 1400, 1500};
    int lvl = blockIdx.x >> 2, b = blockIdx.x & 3;
    int H = Ht[lvl], HW = H * H;
    const float* rw = row + RBt[lvl] + b * H;
    const float* cl = col + RBt[lvl] + b * H;
    const float* bb = basic + ZBt[lvl] + (size_t)b * HW;

    __shared__ float smn[256], smx[256];
    int t = threadIdx.x;
    float rmn, rmx, cmn, cmx, bmn, bmx;

    float mn = 3.4e38f, mx = NEG_BIG;
    for (int h = t; h < H; h += 256) { float v = rw[h]; mn = fminf(mn, v); mx = fmaxf(mx, v); }
    smn[t] = mn; smx[t] = mx; __syncthreads();
    for (int s = 128; s > 0; s >>= 1) { if (t < s) { smn[t] = fminf(smn[t], smn[t+s]); smx[t] = fmaxf(smx[t], smx[t+s]); } __syncthreads(); }
    rmn = smn[0]; rmx = smx[0]; __syncthreads();

    mn = 3.4e38f; mx = NEG_BIG;
    for (int w = t; w < H; w += 256) { float v = cl[w]; mn = fminf(mn, v); mx = fmaxf(mx, v); }
    smn[t] = mn; smx[t] = mx; __syncthreads();
    for (int s = 128; s > 0; s >>= 1) { if (t < s) { smn[t] = fminf(smn[t], smn[t+s]); smx[t] = fmaxf(smx[t], smx[t+s]); } __syncthreads(); }
    cmn = smn[0]; cmx = smx[0]; __syncthreads();

    mn = 3.4e38f; mx = NEG_BIG;
    for (int i = t; i < HW; i += 256) { float v = bb[i]; mn = fminf(mn, v); mx = fmaxf(mx, v); }
    smn[t] = mn; smx[t] = mx; __syncthreads();
    for (int s = 128; s > 0; s >>= 1) { if (t < s) { smn[t] = fminf(smn[t], smn[t+s]); smx[t] = fmaxf(smx[t], smx[t+s]); } __syncthreads(); }
    bmn = smn[0]; bmx = smx[0];

    if (t == 0) {
        float p1 = rmn * cmn, p2 = rmn * cmx, p3 = rmx * cmn, p4 = rmx * cmx;
        float amn = fminf(fminf(p1, p2), fminf(p3, p4));
        float amx = fmaxf(fmaxf(p1, p2), fmaxf(p3, p4));
        float* st = stats + lvl * 16 + b * 4;
        st[0] = amn; st[1] = amx; st[2] = bmn; st[3] = bmx;
    }
}

// ================= distance map fused (in-place over basic) =================
template<int H, int ZB, int RB, int LVL>
__device__ __forceinline__ void dist_impl(int idx, float* __restrict__ basic,
                                          const float* __restrict__ row,
                                          const float* __restrict__ col,
                                          const float* __restrict__ stats)
{
    constexpr int HW = H * H;
    int r = idx - ZB; int b = r / HW; int p = r - b * HW;
    int yh = p / H, xw = p - (p / H) * H;
    const float* st = stats + LVL * 16 + b * 4;
    float amn = st[0], amx = st[1], bmn = st[2], bmx = st[3];
    float an = (row[RB + b * H + yh] * col[RB + b * H + xw] - amn) / (amx - amn + EPSV);
    float bn = (basic[idx] - bmn) / (bmx - bmn + EPSV);
    basic[idx] = cosf((an - bn) * PI_2);
}

__global__ __launch_bounds__(256) void k_dist_f(float* __restrict__ basic,
                                                const float* __restrict__ row,
                                                const float* __restrict__ col,
                                                const float* __restrict__ stats)
{
    int idx = blockIdx.x * 256 + threadIdx.x;
    if (idx >= ZT) return;
    if      (idx < 160000) dist_impl<200, 0,      0,    0>(idx, basic, row, col, stats);
    else if (idx < 200000) dist_impl<100, 160000, 800,  1>(idx, basic, row, col, stats);
    else if (idx < 210000) dist_impl<50,  200000, 1200, 2>(idx, basic, row, col, stats);
    else if (idx < 212500) dist_impl<25,  210000, 1400, 3>(idx, basic, row, col, stats);
    else                   dist_impl<13,  212500, 1500, 4>(idx, basic, row, col, stats);
}

// ================= final fused: out = x + relu(bsf_resized * dist) =================
template<int LVL>
__device__ __forceinline__ void final_impl(int rel, const float* __restrict__ x,
                                           const float* __restrict__ bsf,
                                           const float* __restrict__ dist,
                                           float* __restrict__ out)
{
    constexpr int H = (LVL == 0) ? 200 : (LVL == 1) ? 100 : (LVL == 2) ? 50 : (LVL == 3) ? 25 : 13;
    constexpr int W = H, HW = H * W;
    if constexpr (LVL <= 1) {
        constexpr int Wv = W / 4;
        int vid = rel;
        int xv = vid % Wv; int t = vid / Wv;
        int yh = t % H; t /= H; int c = t % C; int b = t / C;
        f32x4 xw4 = *(const f32x4*)(x + (size_t)vid * 4);
        f32x4 d4  = *(const f32x4*)(dist + (size_t)b * HW + yh * W + xv * 4);
        const float* bb = bsf + ((size_t)b * C + c) * PP;
        f32x4 o;
        if constexpr (LVL == 0) {
            float bv = bb[(yh >> 2) * GW + xv];
            #pragma unroll
            for (int k = 0; k < 4; k++) o[k] = xw4[k] + fmaxf(bv * d4[k], 0.0f);
        } else {
            float bv0 = bb[(yh >> 1) * GW + 2 * xv];
            float bv1 = bb[(yh >> 1) * GW + 2 * xv + 1];
            o[0] = xw4[0] + fmaxf(bv0 * d4[0], 0.0f);
            o[1] = xw4[1] + fmaxf(bv0 * d4[1], 0.0f);
            o[2] = xw4[2] + fmaxf(bv1 * d4[2], 0.0f);
            o[3] = xw4[3] + fmaxf(bv1 * d4[3], 0.0f);
        }
        *(f32x4*)(out + (size_t)vid * 4) = o;
    } else {
        int idx = rel;
        int xw = idx % W; int t = idx / W;
        int yh = t % H; t /= H; int c = t % C; int b = t / C;
        float d = dist[(size_t)b * HW + yh * W + xw];
        constexpr bool ident = (LVL == 2);
        int ry = ident ? yh : (yh * GW) / H;
        int rx = ident ? xw : (xw * GW) / W;
        float bv = bsf[((size_t)b * C + c) * PP + ry * GW + rx];
        out[idx] = x[idx] + fmaxf(bv * d, 0.0f);
    }
}

__global__ __launch_bounds__(256) void k_final_f(
    const float* __restrict__ x0, const float* __restrict__ x1,
    const float* __restrict__ x2, const float* __restrict__ x3,
    const float* __restrict__ x4, const float* __restrict__ bsf,
    const float* __restrict__ basic, float* __restrict__ out)
{
    int bx = blockIdx.x;
    int tid = threadIdx.x;
    if (bx < 40000) {
        final_impl<0>(bx * 256 + tid, x0, bsf, basic, out);
    } else if (bx < 50000) {
        final_impl<1>((bx - 40000) * 256 + tid, x1, bsf, basic + 160000, out + 40960000ull);
    } else if (bx < 60000) {
        final_impl<2>((bx - 50000) * 256 + tid, x2, bsf, basic + 200000, out + 51200000ull);
    } else if (bx < 62500) {
        final_impl<3>((bx - 60000) * 256 + tid, x3, bsf, basic + 210000, out + 53760000ull);
    } else {
        int rel = (bx - 62500) * 256 + tid;
        if (rel < 4 * 256 * 169)
            final_impl<4>(rel, x4, bsf, basic + 212500, out + 54400000ull);
    }
}

// ================= host =================
extern "C" void kernel_launch(void* const* d_in, const int* in_sizes, int n_in,
                              void* d_out, int out_size, void* d_ws, size_t ws_size,
                              hipStream_t stream)
{
    const float* x[5]; for (int i = 0; i < 5; i++) x[i] = (const float*)d_in[i];
    const float* rc_w  = (const float*)d_in[5];
    const float* rc_b  = (const float*)d_in[6];
    const float* g_b   = (const float*)d_in[8];
    const float* th_b  = (const float*)d_in[10];
    const float* ph_b  = (const float*)d_in[12];
    const float* out_b = (const float*)d_in[14];
    float* out = (float*)d_out;

    float* ws    = (float*)d_ws;
    float* ori   = ws + OFF_ORI;
    float* bsf   = ws + OFF_BSF;
    float* zbuf  = ws + OFF_Z;
    float* basic = ws + OFF_BASIC;
    float* rowb  = ws + OFF_ROW;
    float* colb  = ws + OFF_COL;
    float* stats = ws + OFF_STATS;
    unsigned short* u16 = (unsigned short*)(ws + OFF_U16);
    unsigned short* orit = u16 + U_ORIT;
    unsigned short* tht  = u16 + U_THT;
    unsigned short* pht  = u16 + U_PHT;
    unsigned short* gb   = u16 + U_G;
    unsigned short* ytt  = u16 + U_YTT;
    unsigned short* wb   = u16 + U_WB;
    unsigned short* wb_out = wb + 196608;

    // scratch in d_out (fully consumed before k_final_f writes)
    unsigned short* S_all = (unsigned short*)out;            // u16 [4][2560][2560]
    unsigned short* P_all = S_all + 4 * SPB;                 // u16 [4][2560][2560]
    float* part = out + 4 * SPB;                             // fp32 [16][2560][256]

    // 1) pre: wcvt + orife + rowmean + colmean (one launch)
    k_pre<<<11659, 256, 0, stream>>>(
        x[0], x[1], x[2], x[3], x[4],
        (const float*)d_in[9], (const float*)d_in[11],
        (const float*)d_in[7], (const float*)d_in[13],
        wb, ori, rowb, colb);

    // 1b) conv3x3 pass1 (own kernel: full register budget, no barriers)
    k_ctap<<<835, 256, 0, stream>>>(x[0], x[1], x[2], x[3], x[4], rc_w, zbuf);

    // 2) ori transpose+convert
    k_tcvt<<<dim3(PP / 64, C / 64, B), 256, 0, stream>>>(ori, orit);

    // 3) merged projections th/ph/g (z = b*3 + wsel)
    k_proj<<<dim3(20, 2, 12), 256, 0, stream>>>(wb, orit, th_b, ph_b, g_b, tht, pht, gb);

    // small per-level chain (independent of attention)
    k_ccomb_f<<<(ZT + 255) / 256, 256, 0, stream>>>(zbuf, rc_b, basic);
    k_stats_f<<<20, 256, 0, stream>>>(rowb, colb, basic, stats);
    k_dist_f<<<(ZT + 255) / 256, 256, 0, stream>>>(basic, rowb, colb, stats);

    // 4) S = tht @ pht^T  (bf16 out, in d_out)
    dim3 gsc(PP / 128, PP / 128, B);
    k_bgemm<false, false, true><<<gsc, 256, 0, stream>>>(
        tht, pht, nullptr, nullptr, S_all, C, C, C, PP, CPP, CPP, SPB, 0, 1, 0);

    // 5) softmax rows -> P
    k_softmax<<<B * PP, 256, 0, stream>>>(S_all, P_all);

    // 6) yt = P @ g^T, split-K x4, fp32 partials; then reduce -> ytt [p][c]
    dim3 gyt(C / 128, PP / 128, B * 4);
    k_bgemm<false, false, false><<<gyt, 256, 0, stream>>>(
        P_all, gb, nullptr, nullptr, part, PP / 4, PP, PP, C, SPB, CPP, PS, 0, 4, PP / 4);
    k_ytred<<<(B * CPP / 4 + 255) / 256, 256, 0, stream>>>(part, ytt);

    // 7) bsf = out_w @ yt + out_b + ori (fp32)
    dim3 gbsf(PP / 128, C / 128, B);
    k_bgemm<true, true, false><<<gbsf, 256, 0, stream>>>(
        wb_out, ytt, out_b, ori, bsf, C, C, C, PP, 0, CPP, CPP, CPP, 1, 0);

    // 8) finals (one launch, all levels)
    k_final_f<<<63176, 256, 0, stream>>>(
        x[0], x[1], x[2], x[3], x[4], bsf, basic, out);
}

// Round 6
// 369.547 us; speedup vs baseline: 1.1294x; 1.1294x over previous
//
#include <hip/hip_runtime.h>
#include <math.h>

typedef __attribute__((ext_vector_type(8))) short short8;
typedef __attribute__((ext_vector_type(4))) float f32x4;
typedef __attribute__((ext_vector_type(4))) unsigned short u16x4;

#define EPSV 1e-7f
#define PI_2 1.57079632679489662f
#define NEG_BIG (-3.4e38f)

constexpr int B = 4, C = 256;
constexpr int GW = 50;
constexpr int PR = 2500, PP = 2560;              // real / padded 50x50
constexpr int CPP = C * PP;                      // 655,360
constexpr long long SPB = (long long)PP * PP;    // 6,553,600
constexpr int PS = PP * C;                       // partial slice
constexpr int ZT = 213176;                       // sum_l B*H_l*W_l

// ---- workspace float offsets ----
constexpr size_t OFF_ORI   = 0;                            // fp32 [4][256][2560]
constexpr size_t OFF_BSF   = OFF_ORI + (size_t)B * CPP;
constexpr size_t OFF_Z     = OFF_BSF + (size_t)B * CPP;    // fp32 [9][ZT]
constexpr size_t OFF_BASIC = OFF_Z + (size_t)9 * ZT;
constexpr size_t OFF_ROW   = OFF_BASIC + 213184;
constexpr size_t OFF_COL   = OFF_ROW + 1600;
constexpr size_t OFF_STATS = OFF_COL + 1600;
constexpr size_t OFF_U16   = OFF_STATS + 128;
// ---- u16 offsets within u16 region ----
constexpr size_t U_ORIT = 0;                               // [4][2560][256]
constexpr size_t U_THT  = U_ORIT + (size_t)B * CPP;
constexpr size_t U_PHT  = U_THT  + (size_t)B * CPP;
constexpr size_t U_G    = U_PHT  + (size_t)B * CPP;        // [4][256][2560]
constexpr size_t U_YTT  = U_G    + (size_t)B * CPP;        // [4][2560][256]
constexpr size_t U_WB   = U_YTT  + (size_t)B * CPP;        // 4 x [256][256]

__device__ __forceinline__ unsigned short f2b(float x) {
    union { float f; unsigned u; } q{x};
    unsigned r = q.u + 0x7FFFu + ((q.u >> 16) & 1u);
    return (unsigned short)(r >> 16);
}
__device__ __forceinline__ float b2f(unsigned short u) {
    union { unsigned u; float f; } q{(unsigned)u << 16};
    return q.f;
}

// ---- ori_fe single-element body ----
__device__ __forceinline__ float orife_val(
    int idx, const float* __restrict__ x0, const float* __restrict__ x1,
    const float* __restrict__ x2, const float* __restrict__ x3,
    const float* __restrict__ x4)
{
    int p = idx % PP; int bc = idx / PP;
    if (p >= PR) return 0.0f;
    int y = p / GW, x = p % GW;
    const float* p0 = x0 + (size_t)bc * 40000;
    float m0 = NEG_BIG;
    #pragma unroll
    for (int dy = 0; dy < 4; dy++) {
        f32x4 r = *(const f32x4*)(p0 + (y * 4 + dy) * 200 + x * 4);
        m0 = fmaxf(m0, fmaxf(fmaxf(r[0], r[1]), fmaxf(r[2], r[3])));
    }
    const float* p1 = x1 + (size_t)bc * 10000;
    float m1 = fmaxf(fmaxf(p1[(y*2)*100 + x*2],   p1[(y*2)*100 + x*2+1]),
                     fmaxf(p1[(y*2+1)*100 + x*2], p1[(y*2+1)*100 + x*2+1]));
    float v2 = x2[(size_t)bc * 2500 + p];
    float v3 = x3[(size_t)bc * 625 + (y/2)*25 + (x/2)];
    int ry = (y * 13) / 50, rx = (x * 13) / 50;
    float v4 = x4[(size_t)bc * 169 + ry * 13 + rx];
    return (m0 + m1 + v2 + v3 + v4) * 0.2f;
}

// ================= k_pre: rowm | colm | wcvt | orife(x4 batched) =================
// block ranges: [0,388) rowm, [388,395) colm, [395,1419) wcvt, [1419,3979) orife
constexpr int ORIFE_T = 2560 * 256;   // threads in orife segment

__global__ __launch_bounds__(256) void k_pre(
    const float* __restrict__ x0, const float* __restrict__ x1,
    const float* __restrict__ x2, const float* __restrict__ x3,
    const float* __restrict__ x4,
    const float* __restrict__ wth, const float* __restrict__ wph,
    const float* __restrict__ wg,  const float* __restrict__ wout,
    unsigned short* __restrict__ wb, float* __restrict__ ori,
    float* __restrict__ row, float* __restrict__ col)
{
    const int bx = blockIdx.x;
    const int tid = threadIdx.x;

    if (bx < 388) {
        // ---- row means: 4 rows/block, one per wave ----
        int rid = bx * 4 + (tid >> 6);
        int lane = tid & 63;
        int base, H; const float* x;
        if      (rid < 800)  { base = 0;    H = 200; x = x0; }
        else if (rid < 1200) { base = 800;  H = 100; x = x1; }
        else if (rid < 1400) { base = 1200; H = 50;  x = x2; }
        else if (rid < 1500) { base = 1400; H = 25;  x = x3; }
        else                 { base = 1500; H = 13;  x = x4; }
        int r = rid - base; int b = r / H, h = r - (r / H) * H;
        const float* xr = x + (size_t)b * C * H * H + (size_t)h * H;
        float s = 0.0f;
        for (int w = lane; w < H; w += 64) s += xr[w];
        #pragma unroll
        for (int off = 32; off > 0; off >>= 1) s += __shfl_down(s, off);
        if (lane == 0) row[rid] = s / (float)H;
    } else if (bx < 395) {
        // ---- col means: thread per (lvl,b,w), 4 load streams ----
        int idx = (bx - 388) * 256 + tid;
        if (idx >= 1552) return;
        int base, H; const float* x;
        if      (idx < 800)  { base = 0;    H = 200; x = x0; }
        else if (idx < 1200) { base = 800;  H = 100; x = x1; }
        else if (idx < 1400) { base = 1200; H = 50;  x = x2; }
        else if (idx < 1500) { base = 1400; H = 25;  x = x3; }
        else                 { base = 1500; H = 13;  x = x4; }
        int r = idx - base; int b = r / H, w = r - (r / H) * H;
        const float* xc = x + (size_t)b * C * H * H + w;
        float s = 0.0f;
        int h = 0;
        for (; h + 3 < H; h += 4) {
            float a0 = xc[(size_t)h * H];
            float a1 = xc[(size_t)(h + 1) * H];
            float a2 = xc[(size_t)(h + 2) * H];
            float a3 = xc[(size_t)(h + 3) * H];
            s += (a0 + a1) + (a2 + a3);
        }
        for (; h < H; h++) s += xc[(size_t)h * H];
        col[idx] = s / (float)H;
    } else if (bx < 1419) {
        // ---- weight convert: 4 x 256x256 ----
        int idx = (bx - 395) * 256 + tid;
        int seg = idx >> 16, off = idx & 65535;
        const float* s = (seg == 0) ? wth : (seg == 1) ? wph : (seg == 2) ? wg : wout;
        wb[idx] = f2b(s[off]);
    } else {
        // ---- ori_fe gather: 4 outputs/thread, strided (coalesced) ----
        int t0 = (bx - 1419) * 256 + tid;
        #pragma unroll
        for (int k = 0; k < 4; k++) {
            int idx = t0 + k * ORIFE_T;
            ori[idx] = orife_val(idx, x0, x1, x2, x3, x4);
        }
    }
}

// ================= conv3x3 pass1: 1 px/thread, 8-wide channel batches =================
__global__ __launch_bounds__(256) void k_ctap(
    const float* __restrict__ x0, const float* __restrict__ x1,
    const float* __restrict__ x2, const float* __restrict__ x3,
    const float* __restrict__ x4, const float* __restrict__ rc_w,
    float* __restrict__ z)
{
    __shared__ float wsm[C * 12];
    const int bx = blockIdx.x;
    const int tid = threadIdx.x;

    int lvl, base, HW, zb; const float* x;
    if      (bx < 625) { lvl = 0; base = 0;   HW = 40000; zb = 0;      x = x0; }
    else if (bx < 782) { lvl = 1; base = 625; HW = 10000; zb = 160000; x = x1; }
    else if (bx < 822) { lvl = 2; base = 782; HW = 2500;  zb = 200000; x = x2; }
    else if (bx < 832) { lvl = 3; base = 822; HW = 625;   zb = 210000; x = x3; }
    else               { lvl = 4; base = 832; HW = 169;   zb = 212500; x = x4; }

    const float* w9 = rc_w + (size_t)lvl * C * 9;
    for (int i = tid; i < C * 9; i += 256) wsm[(i / 9) * 12 + (i % 9)] = w9[i];
    __syncthreads();

    int idx = (bx - base) * 256 + tid;
    if (idx >= B * HW) return;
    int b = idx / HW, p = idx - b * HW;

    float acc[9] = {};
    const float* xp = x + (size_t)b * C * HW + p;
    for (int c0 = 0; c0 < C; c0 += 8) {
        float v[8];
        #pragma unroll
        for (int k = 0; k < 8; k++) v[k] = xp[(size_t)(c0 + k) * HW];
        #pragma unroll
        for (int k = 0; k < 8; k++) {
            const float* wc = &wsm[(c0 + k) * 12];
            f32x4 w0 = *(const f32x4*)wc;
            f32x4 w1 = *(const f32x4*)(wc + 4);
            float w8 = wc[8];
            acc[0] += v[k] * w0[0]; acc[1] += v[k] * w0[1];
            acc[2] += v[k] * w0[2]; acc[3] += v[k] * w0[3];
            acc[4] += v[k] * w1[0]; acc[5] += v[k] * w1[1];
            acc[6] += v[k] * w1[2]; acc[7] += v[k] * w1[3];
            acc[8] += v[k] * w8;
        }
    }
    #pragma unroll
    for (int t = 0; t < 9; t++)
        z[(size_t)t * ZT + zb + idx] = acc[t];
}

// ================= transpose+convert: ori fp32 [b][c][p] -> u16 [b][p][c] =================
__global__ __launch_bounds__(256) void k_tcvt(const float* __restrict__ ori,
                                              unsigned short* __restrict__ ot)
{
    __shared__ unsigned short t[64][66];
    int p0 = blockIdx.x * 64, c0 = blockIdx.y * 64, b = blockIdx.z;
    int pp = threadIdx.x & 63, cb = threadIdx.x >> 6;
    #pragma unroll
    for (int i = 0; i < 16; i++) {
        int cc = cb * 16 + i;
        t[cc][pp] = f2b(ori[((size_t)b * C + c0 + cc) * PP + p0 + pp]);
    }
    __syncthreads();
    int cc2 = threadIdx.x & 63, pb = threadIdx.x >> 6;
    #pragma unroll
    for (int i = 0; i < 16; i++) {
        int pp2 = pb * 16 + i;
        ot[((size_t)b * PP + p0 + pp2) * C + c0 + cc2] = t[cc2][pp2];
    }
}

// ================= merged projections (th, ph, g) =================
constexpr int LDT = 40;

__global__ __launch_bounds__(256) void k_proj(
    const unsigned short* __restrict__ wb, const unsigned short* __restrict__ orit,
    const float* __restrict__ th_b, const float* __restrict__ ph_b,
    const float* __restrict__ g_b,
    unsigned short* __restrict__ tht, unsigned short* __restrict__ pht,
    unsigned short* __restrict__ gb)
{
    __shared__ __align__(16) unsigned short As[128 * LDT];
    __shared__ __align__(16) unsigned short Bs[128 * LDT];

    const int z = blockIdx.z;
    const int b = z / 3, wsel = z - b * 3;
    const bool tp = (wsel < 2);
    const unsigned short* A = tp ? (orit + (size_t)b * CPP) : (wb + 131072);
    const unsigned short* Bm = tp ? (wb + wsel * 65536) : (orit + (size_t)b * CPP);
    const float* bias = (wsel == 0) ? th_b : (wsel == 1) ? ph_b : g_b;

    const int m0 = (tp ? blockIdx.x : blockIdx.y) * 128;
    const int n0 = (tp ? blockIdx.y : blockIdx.x) * 128;
    const int tid = threadIdx.x;
    const int lane = tid & 63, w = tid >> 6;
    const int wm = (w & 1) * 64, wn = (w >> 1) * 64;
    const int fr = lane & 15, fq = lane >> 4;

    f32x4 acc[4][4] = {};
    for (int k0 = 0; k0 < 256; k0 += 32) {
        #pragma unroll
        for (int l = 0; l < 2; l++) {
            int li = tid + l * 256;
            int rr = li >> 2, kc = li & 3;
            short8 va = *(const short8*)(A  + (size_t)(m0 + rr) * 256 + k0 + kc * 8);
            short8 vb = *(const short8*)(Bm + (size_t)(n0 + rr) * 256 + k0 + kc * 8);
            *(short8*)&As[rr * LDT + kc * 8] = va;
            *(short8*)&Bs[rr * LDT + kc * 8] = vb;
        }
        __syncthreads();
        short8 af[4], bf[4];
        #pragma unroll
        for (int i = 0; i < 4; i++)
            af[i] = *(const short8*)&As[(wm + i * 16 + fr) * LDT + fq * 8];
        #pragma unroll
        for (int j = 0; j < 4; j++)
            bf[j] = *(const short8*)&Bs[(wn + j * 16 + fr) * LDT + fq * 8];
        #pragma unroll
        for (int i = 0; i < 4; i++)
            #pragma unroll
            for (int j = 0; j < 4; j++)
                acc[i][j] = __builtin_amdgcn_mfma_f32_16x16x32_bf16(
                    af[i], bf[j], acc[i][j], 0, 0, 0);
        __syncthreads();
    }

    unsigned short* dst = (wsel == 0) ? tht : (wsel == 1) ? pht : gb;
    dst += (size_t)b * CPP;
    #pragma unroll
    for (int i = 0; i < 4; i++) {
        #pragma unroll
        for (int r = 0; r < 4; r++) {
            int gm = m0 + wm + i * 16 + fq * 4 + r;
            #pragma unroll
            for (int j = 0; j < 4; j++) {
                int gn = n0 + wn + j * 16 + fr;
                float v = acc[i][j][r] + (tp ? bias[gn] : bias[gm]);
                size_t off = tp ? ((size_t)gm * 256 + gn) : ((size_t)gm * PP + gn);
                dst[off] = f2b(v);
            }
        }
    }
}

// ================= generic bf16 MFMA GEMM: C = A[M][K] * B[N][K]^T =================
template<bool AddBias, bool AddRes, bool OutBf>
__global__ __launch_bounds__(256) void k_bgemm(
    const unsigned short* __restrict__ A, const unsigned short* __restrict__ Bm,
    const float* __restrict__ bias, const float* __restrict__ res,
    void* __restrict__ Cout, int K, int lda, int ldb, int ldc,
    long long sA, long long sB, long long sC, long long sR,
    int nsplit, long long sK)
{
    __shared__ __align__(16) unsigned short As[128 * LDT];
    __shared__ __align__(16) unsigned short Bs[128 * LDT];

    const int z = blockIdx.z;
    const int bz = z / nsplit, ks = z - bz * nsplit;
    A  += (size_t)sA * bz + (size_t)sK * ks;
    Bm += (size_t)sB * bz + (size_t)sK * ks;

    const int m0 = blockIdx.y * 128, n0 = blockIdx.x * 128;
    const int tid = threadIdx.x;
    const int lane = tid & 63, w = tid >> 6;
    const int wm = (w & 1) * 64, wn = (w >> 1) * 64;
    const int fr = lane & 15, fq = lane >> 4;

    f32x4 acc[4][4] = {};
    for (int k0 = 0; k0 < K; k0 += 32) {
        #pragma unroll
        for (int l = 0; l < 2; l++) {
            int li = tid + l * 256;
            int rr = li >> 2, kc = li & 3;
            short8 va = *(const short8*)(A  + (size_t)(m0 + rr) * lda + k0 + kc * 8);
            short8 vb = *(const short8*)(Bm + (size_t)(n0 + rr) * ldb + k0 + kc * 8);
            *(short8*)&As[rr * LDT + kc * 8] = va;
            *(short8*)&Bs[rr * LDT + kc * 8] = vb;
        }
        __syncthreads();
        short8 af[4], bf[4];
        #pragma unroll
        for (int i = 0; i < 4; i++)
            af[i] = *(const short8*)&As[(wm + i * 16 + fr) * LDT + fq * 8];
        #pragma unroll
        for (int j = 0; j < 4; j++)
            bf[j] = *(const short8*)&Bs[(wn + j * 16 + fr) * LDT + fq * 8];
        #pragma unroll
        for (int i = 0; i < 4; i++)
            #pragma unroll
            for (int j = 0; j < 4; j++)
                acc[i][j] = __builtin_amdgcn_mfma_f32_16x16x32_bf16(
                    af[i], bf[j], acc[i][j], 0, 0, 0);
        __syncthreads();
    }

    float* Cf = (float*)Cout;
    unsigned short* Cb = (unsigned short*)Cout;
    const size_t co = (size_t)sC * z;
    const size_t ro = (size_t)sR * bz;
    #pragma unroll
    for (int i = 0; i < 4; i++) {
        #pragma unroll
        for (int r = 0; r < 4; r++) {
            int gm = m0 + wm + i * 16 + fq * 4 + r;
            #pragma unroll
            for (int j = 0; j < 4; j++) {
                int gn = n0 + wn + j * 16 + fr;
                float v = acc[i][j][r];
                if (AddBias) v += bias[gm];
                if (AddRes)  v += res[ro + (size_t)gm * ldc + gn];
                size_t off = co + (size_t)gm * ldc + gn;
                if (OutBf) Cb[off] = f2b(v);
                else       Cf[off] = v;
            }
        }
    }
}

// ================= yt split-K reduce: 4 fp32 partials -> bf16 ytt =================
__global__ __launch_bounds__(256) void k_ytred(const float* __restrict__ part,
                                               unsigned short* __restrict__ ytt)
{
    int idx = blockIdx.x * 256 + threadIdx.x;
    if (idx >= B * CPP / 4) return;
    int b = idx / (CPP / 4);
    int r = idx - b * (CPP / 4);
    const float* p = part + (size_t)(b * 4) * PS + (size_t)r * 4;
    f32x4 s = *(const f32x4*)p;
    #pragma unroll
    for (int ks = 1; ks < 4; ks++) {
        f32x4 q = *(const f32x4*)(p + (size_t)ks * PS);
        s[0] += q[0]; s[1] += q[1]; s[2] += q[2]; s[3] += q[3];
    }
    u16x4 o;
    #pragma unroll
    for (int k = 0; k < 4; k++) o[k] = f2b(s[k]);
    *(u16x4*)(ytt + (size_t)b * CPP + (size_t)r * 4) = o;
}

// ================= row softmax: bf16 S rows -> bf16 P rows =================
__global__ __launch_bounds__(256) void k_softmax(const unsigned short* __restrict__ S,
                                                 unsigned short* __restrict__ P)
{
    __shared__ float red[256];
    const int row = blockIdx.x;
    const unsigned short* r = S + (size_t)row * PP;
    unsigned short* p = P + (size_t)row * PP;
    const int t = threadIdx.x;
    float v[10];
    float mx = NEG_BIG;
    #pragma unroll
    for (int i = 0; i < 10; i++) {
        int j = i * 256 + t;
        v[i] = (j < PR) ? b2f(r[j]) : NEG_BIG;
        mx = fmaxf(mx, v[i]);
    }
    red[t] = mx; __syncthreads();
    for (int s = 128; s > 0; s >>= 1) { if (t < s) red[t] = fmaxf(red[t], red[t+s]); __syncthreads(); }
    mx = red[0]; __syncthreads();
    float sum = 0.0f;
    #pragma unroll
    for (int i = 0; i < 10; i++) { float e = __expf(v[i] - mx); v[i] = e; sum += e; }
    red[t] = sum; __syncthreads();
    for (int s = 128; s > 0; s >>= 1) { if (t < s) red[t] += red[t+s]; __syncthreads(); }
    float inv = 1.0f / red[0];
    #pragma unroll
    for (int i = 0; i < 10; i++) p[i * 256 + t] = f2b(v[i] * inv);
}

// ================= conv3x3 pass2 fused =================
template<int H, int ZB>
__device__ __forceinline__ void ccomb_impl(int idx, const float* __restrict__ z,
                                           float biasv, float* __restrict__ bas)
{
    constexpr int W = H, HW = H * W;
    int r = idx - ZB; int b = r / HW; int p = r - b * HW;
    int y = p / W, x = p - (p / W) * W;
    float acc = biasv;
    #pragma unroll
    for (int dy = 0; dy < 3; dy++) {
        int yy = y + dy - 1;
        if (yy < 0 || yy >= H) continue;
        #pragma unroll
        for (int dx = 0; dx < 3; dx++) {
            int xx = x + dx - 1;
            if (xx < 0 || xx >= W) continue;
            acc += z[(size_t)(dy * 3 + dx) * ZT + ZB + (size_t)b * HW + yy * W + xx];
        }
    }
    bas[idx] = fmaxf(acc, 0.0f);
}

__global__ __launch_bounds__(256) void k_ccomb_f(const float* __restrict__ z,
                                                 const float* __restrict__ rb,
                                                 float* __restrict__ bas)
{
    int idx = blockIdx.x * 256 + threadIdx.x;
    if (idx >= ZT) return;
    if      (idx < 160000) ccomb_impl<200, 0>     (idx, z, rb[0], bas);
    else if (idx < 200000) ccomb_impl<100, 160000>(idx, z, rb[1], bas);
    else if (idx < 210000) ccomb_impl<50,  200000>(idx, z, rb[2], bas);
    else if (idx < 212500) ccomb_impl<25,  210000>(idx, z, rb[3], bas);
    else                   ccomb_impl<13,  212500>(idx, z, rb[4], bas);
}

// ================= per-sample stats fused (block per (lvl,b)) =================
__global__ __launch_bounds__(256) void k_stats_f(
    const float* __restrict__ row, const float* __restrict__ col,
    const float* __restrict__ basic, float* __restrict__ stats)
{
    const int Ht[5]  = {200, 100, 50, 25, 13};
    const int ZBt[5] = {0, 160000, 200000, 210000, 212500};
    const int RBt[5] = {0, 800, 1200, 1400, 1500};
    int lvl = blockIdx.x >> 2, b = blockIdx.x & 3;
    int H = Ht[lvl], HW = H * H;
    const float* rw = row + RBt[lvl] + b * H;
    const float* cl = col + RBt[lvl] + b * H;
    const float* bb = basic + ZBt[lvl] + (size_t)b * HW;

    __shared__ float smn[256], smx[256];
    int t = threadIdx.x;
    float rmn, rmx, cmn, cmx, bmn, bmx;

    float mn = 3.4e38f, mx = NEG_BIG;
    for (int h = t; h < H; h += 256) { float v = rw[h]; mn = fminf(mn, v); mx = fmaxf(mx, v); }
    smn[t] = mn; smx[t] = mx; __syncthreads();
    for (int s = 128; s > 0; s >>= 1) { if (t < s) { smn[t] = fminf(smn[t], smn[t+s]); smx[t] = fmaxf(smx[t], smx[t+s]); } __syncthreads(); }
    rmn = smn[0]; rmx = smx[0]; __syncthreads();

    mn = 3.4e38f; mx = NEG_BIG;
    for (int w = t; w < H; w += 256) { float v = cl[w]; mn = fminf(mn, v); mx = fmaxf(mx, v); }
    smn[t] = mn; smx[t] = mx; __syncthreads();
    for (int s = 128; s > 0; s >>= 1) { if (t < s) { smn[t] = fminf(smn[t], smn[t+s]); smx[t] = fmaxf(smx[t], smx[t+s]); } __syncthreads(); }
    cmn = smn[0]; cmx = smx[0]; __syncthreads();

    mn = 3.4e38f; mx = NEG_BIG;
    for (int i = t; i < HW; i += 256) { float v = bb[i]; mn = fminf(mn, v); mx = fmaxf(mx, v); }
    smn[t] = mn; smx[t] = mx; __syncthreads();
    for (int s = 128; s > 0; s >>= 1) { if (t < s) { smn[t] = fminf(smn[t], smn[t+s]); smx[t] = fmaxf(smx[t], smx[t+s]); } __syncthreads(); }
    bmn = smn[0]; bmx = smx[0];

    if (t == 0) {
        float p1 = rmn * cmn, p2 = rmn * cmx, p3 = rmx * cmn, p4 = rmx * cmx;
        float amn = fminf(fminf(p1, p2), fminf(p3, p4));
        float amx = fmaxf(fmaxf(p1, p2), fmaxf(p3, p4));
        float* st = stats + lvl * 16 + b * 4;
        st[0] = amn; st[1] = amx; st[2] = bmn; st[3] = bmx;
    }
}

// ================= distance map fused (in-place over basic) =================
template<int H, int ZB, int RB, int LVL>
__device__ __forceinline__ void dist_impl(int idx, float* __restrict__ basic,
                                          const float* __restrict__ row,
                                          const float* __restrict__ col,
                                          const float* __restrict__ stats)
{
    constexpr int HW = H * H;
    int r = idx - ZB; int b = r / HW; int p = r - b * HW;
    int yh = p / H, xw = p - (p / H) * H;
    const float* st = stats + LVL * 16 + b * 4;
    float amn = st[0], amx = st[1], bmn = st[2], bmx = st[3];
    float an = (row[RB + b * H + yh] * col[RB + b * H + xw] - amn) / (amx - amn + EPSV);
    float bn = (basic[idx] - bmn) / (bmx - bmn + EPSV);
    basic[idx] = cosf((an - bn) * PI_2);
}

__global__ __launch_bounds__(256) void k_dist_f(float* __restrict__ basic,
                                                const float* __restrict__ row,
                                                const float* __restrict__ col,
                                                const float* __restrict__ stats)
{
    int idx = blockIdx.x * 256 + threadIdx.x;
    if (idx >= ZT) return;
    if      (idx < 160000) dist_impl<200, 0,      0,    0>(idx, basic, row, col, stats);
    else if (idx < 200000) dist_impl<100, 160000, 800,  1>(idx, basic, row, col, stats);
    else if (idx < 210000) dist_impl<50,  200000, 1200, 2>(idx, basic, row, col, stats);
    else if (idx < 212500) dist_impl<25,  210000, 1400, 3>(idx, basic, row, col, stats);
    else                   dist_impl<13,  212500, 1500, 4>(idx, basic, row, col, stats);
}

// ================= final: out = x + relu(bsf_resized * dist), batched =================
template<int LVL>
__device__ __forceinline__ void final_v4(int vid, const float* __restrict__ x,
                                         const float* __restrict__ bsf,
                                         const float* __restrict__ dist,
                                         float* __restrict__ out)
{
    constexpr int H = (LVL == 0) ? 200 : 100;
    constexpr int W = H, HW = H * W, Wv = W / 4;
    int xv = vid % Wv; int t = vid / Wv;
    int yh = t % H; t /= H; int c = t % C; int b = t / C;
    f32x4 xw4 = *(const f32x4*)(x + (size_t)vid * 4);
    f32x4 d4  = *(const f32x4*)(dist + (size_t)b * HW + yh * W + xv * 4);
    const float* bb = bsf + ((size_t)b * C + c) * PP;
    f32x4 o;
    if constexpr (LVL == 0) {
        float bv = bb[(yh >> 2) * GW + xv];
        #pragma unroll
        for (int k = 0; k < 4; k++) o[k] = xw4[k] + fmaxf(bv * d4[k], 0.0f);
    } else {
        float bv0 = bb[(yh >> 1) * GW + 2 * xv];
        float bv1 = bb[(yh >> 1) * GW + 2 * xv + 1];
        o[0] = xw4[0] + fmaxf(bv0 * d4[0], 0.0f);
        o[1] = xw4[1] + fmaxf(bv0 * d4[1], 0.0f);
        o[2] = xw4[2] + fmaxf(bv1 * d4[2], 0.0f);
        o[3] = xw4[3] + fmaxf(bv1 * d4[3], 0.0f);
    }
    *(f32x4*)(out + (size_t)vid * 4) = o;
}

template<int LVL>
__device__ __forceinline__ void final_s(int idx, const float* __restrict__ x,
                                        const float* __restrict__ bsf,
                                        const float* __restrict__ dist,
                                        float* __restrict__ out)
{
    constexpr int H = (LVL == 2) ? 50 : (LVL == 3) ? 25 : 13;
    constexpr int W = H, HW = H * W;
    int xw = idx % W; int t = idx / W;
    int yh = t % H; t /= H; int c = t % C; int b = t / C;
    float d = dist[(size_t)b * HW + yh * W + xw];
    constexpr bool ident = (LVL == 2);
    int ry = ident ? yh : (yh * GW) / H;
    int rx = ident ? xw : (xw * GW) / W;
    float bv = bsf[((size_t)b * C + c) * PP + ry * GW + rx];
    out[idx] = x[idx] + fmaxf(bv * d, 0.0f);
}

// block ranges: L0 [0,8000) x5 vec, L1 [8000,10000) x5 vec,
//               L2 [10000,12000) x5 scalar, L3 [12000,12500) x5, L4 [12500,12669) x4
__global__ __launch_bounds__(256) void k_final_f(
    const float* __restrict__ x0, const float* __restrict__ x1,
    const float* __restrict__ x2, const float* __restrict__ x3,
    const float* __restrict__ x4, const float* __restrict__ bsf,
    const float* __restrict__ basic, float* __restrict__ out)
{
    int bx = blockIdx.x;
    int tid = threadIdx.x;
    if (bx < 8000) {
        int t0 = bx * 256 + tid;                       // 2,048,000 threads
        #pragma unroll
        for (int k = 0; k < 5; k++)
            final_v4<0>(t0 + k * 2048000, x0, bsf, basic, out);
    } else if (bx < 10000) {
        int t0 = (bx - 8000) * 256 + tid;              // 512,000 threads
        #pragma unroll
        for (int k = 0; k < 5; k++)
            final_v4<1>(t0 + k * 512000, x1, bsf, basic + 160000, out + 40960000ull);
    } else if (bx < 12000) {
        int t0 = (bx - 10000) * 256 + tid;             // 512,000 threads, scalar
        #pragma unroll
        for (int k = 0; k < 5; k++)
            final_s<2>(t0 + k * 512000, x2, bsf, basic + 200000, out + 51200000ull);
    } else if (bx < 12500) {
        int t0 = (bx - 12000) * 256 + tid;             // 128,000 threads
        #pragma unroll
        for (int k = 0; k < 5; k++)
            final_s<3>(t0 + k * 128000, x3, bsf, basic + 210000, out + 53760000ull);
    } else {
        int t0 = (bx - 12500) * 256 + tid;             // 43,264 threads
        #pragma unroll
        for (int k = 0; k < 4; k++)
            final_s<4>(t0 + k * 43264, x4, bsf, basic + 212500, out + 54400000ull);
    }
}

// ================= host =================
extern "C" void kernel_launch(void* const* d_in, const int* in_sizes, int n_in,
                              void* d_out, int out_size, void* d_ws, size_t ws_size,
                              hipStream_t stream)
{
    const float* x[5]; for (int i = 0; i < 5; i++) x[i] = (const float*)d_in[i];
    const float* rc_w  = (const float*)d_in[5];
    const float* rc_b  = (const float*)d_in[6];
    const float* g_b   = (const float*)d_in[8];
    const float* th_b  = (const float*)d_in[10];
    const float* ph_b  = (const float*)d_in[12];
    const float* out_b = (const float*)d_in[14];
    float* out = (float*)d_out;

    float* ws    = (float*)d_ws;
    float* ori   = ws + OFF_ORI;
    float* bsf   = ws + OFF_BSF;
    float* zbuf  = ws + OFF_Z;
    float* basic = ws + OFF_BASIC;
    float* rowb  = ws + OFF_ROW;
    float* colb  = ws + OFF_COL;
    float* stats = ws + OFF_STATS;
    unsigned short* u16 = (unsigned short*)(ws + OFF_U16);
    unsigned short* orit = u16 + U_ORIT;
    unsigned short* tht  = u16 + U_THT;
    unsigned short* pht  = u16 + U_PHT;
    unsigned short* gb   = u16 + U_G;
    unsigned short* ytt  = u16 + U_YTT;
    unsigned short* wb   = u16 + U_WB;
    unsigned short* wb_out = wb + 196608;

    // scratch in d_out (fully consumed before k_final_f writes)
    unsigned short* S_all = (unsigned short*)out;            // u16 [4][2560][2560]
    unsigned short* P_all = S_all + 4 * SPB;                 // u16 [4][2560][2560]
    float* part = out + 4 * SPB;                             // fp32 [16][2560][256]

    // 1) pre: rowm + colm + wcvt + orife (one launch, batched orife)
    k_pre<<<3979, 256, 0, stream>>>(
        x[0], x[1], x[2], x[3], x[4],
        (const float*)d_in[9], (const float*)d_in[11],
        (const float*)d_in[7], (const float*)d_in[13],
        wb, ori, rowb, colb);

    // 1b) conv3x3 pass1 (8-wide channel batches)
    k_ctap<<<835, 256, 0, stream>>>(x[0], x[1], x[2], x[3], x[4], rc_w, zbuf);

    // 2) ori transpose+convert
    k_tcvt<<<dim3(PP / 64, C / 64, B), 256, 0, stream>>>(ori, orit);

    // 3) merged projections th/ph/g (z = b*3 + wsel)
    k_proj<<<dim3(20, 2, 12), 256, 0, stream>>>(wb, orit, th_b, ph_b, g_b, tht, pht, gb);

    // small per-level chain (independent of attention)
    k_ccomb_f<<<(ZT + 255) / 256, 256, 0, stream>>>(zbuf, rc_b, basic);
    k_stats_f<<<20, 256, 0, stream>>>(rowb, colb, basic, stats);
    k_dist_f<<<(ZT + 255) / 256, 256, 0, stream>>>(basic, rowb, colb, stats);

    // 4) S = tht @ pht^T  (bf16 out, in d_out)
    dim3 gsc(PP / 128, PP / 128, B);
    k_bgemm<false, false, true><<<gsc, 256, 0, stream>>>(
        tht, pht, nullptr, nullptr, S_all, C, C, C, PP, CPP, CPP, SPB, 0, 1, 0);

    // 5) softmax rows -> P
    k_softmax<<<B * PP, 256, 0, stream>>>(S_all, P_all);

    // 6) yt = P @ g^T, split-K x4, fp32 partials; then reduce -> ytt [p][c]
    dim3 gyt(C / 128, PP / 128, B * 4);
    k_bgemm<false, false, false><<<gyt, 256, 0, stream>>>(
        P_all, gb, nullptr, nullptr, part, PP / 4, PP, PP, C, SPB, CPP, PS, 0, 4, PP / 4);
    k_ytred<<<(B * CPP / 4 + 255) / 256, 256, 0, stream>>>(part, ytt);

    // 7) bsf = out_w @ yt + out_b + ori (fp32)
    dim3 gbsf(PP / 128, C / 128, B);
    k_bgemm<true, true, false><<<gbsf, 256, 0, stream>>>(
        wb_out, ytt, out_b, ori, bsf, C, C, C, PP, 0, CPP, CPP, CPP, 1, 0);

    // 8) finals (one launch, all levels, 5x/4x batched)
    k_final_f<<<12669, 256, 0, stream>>>(
        x[0], x[1], x[2], x[3], x[4], bsf, basic, out);
}

// Round 7
// 347.650 us; speedup vs baseline: 1.2005x; 1.0630x over previous
//
#include <hip/hip_runtime.h>
#include <math.h>

typedef __attribute__((ext_vector_type(8))) short short8;
typedef __attribute__((ext_vector_type(4))) float f32x4;
typedef __attribute__((ext_vector_type(4))) unsigned short u16x4;

#define EPSV 1e-7f
#define PI_2 1.57079632679489662f
#define NEG_BIG (-3.4e38f)

constexpr int B = 4, C = 256;
constexpr int GW = 50;
constexpr int PR = 2500, PP = 2560;              // real / padded 50x50
constexpr int CPP = C * PP;                      // 655,360
constexpr long long SPB = (long long)PP * PP;    // 6,553,600
constexpr int PS = PP * C;                       // partial slice
constexpr int ZT = 213176;                       // sum_l B*H_l*W_l

// ---- workspace float offsets ----
constexpr size_t OFF_ORI   = 0;                            // fp32 [4][256][2560]
constexpr size_t OFF_BSF   = OFF_ORI + (size_t)B * CPP;    // u16 [4][256][2560] (bf16 bsf)
constexpr size_t OFF_Z     = OFF_BSF + (size_t)B * CPP;    // fp32 [9][ZT]
constexpr size_t OFF_BASIC = OFF_Z + (size_t)9 * ZT;
constexpr size_t OFF_ROW   = OFF_BASIC + 213184;
constexpr size_t OFF_COL   = OFF_ROW + 1600;
constexpr size_t OFF_STATS = OFF_COL + 1600;
constexpr size_t OFF_U16   = OFF_STATS + 128;
// ---- u16 offsets within u16 region ----
constexpr size_t U_ORIT = 0;                               // [4][2560][256]
constexpr size_t U_THT  = U_ORIT + (size_t)B * CPP;
constexpr size_t U_PHT  = U_THT  + (size_t)B * CPP;
constexpr size_t U_G    = U_PHT  + (size_t)B * CPP;        // [4][256][2560]
constexpr size_t U_YTT  = U_G    + (size_t)B * CPP;        // [4][2560][256]
constexpr size_t U_WB   = U_YTT  + (size_t)B * CPP;        // 4 x [256][256]

__device__ __forceinline__ unsigned short f2b(float x) {
    union { float f; unsigned u; } q{x};
    unsigned r = q.u + 0x7FFFu + ((q.u >> 16) & 1u);
    return (unsigned short)(r >> 16);
}
__device__ __forceinline__ float b2f(unsigned short u) {
    union { unsigned u; float f; } q{(unsigned)u << 16};
    return q.f;
}

// ---- ori_fe single-element body ----
__device__ __forceinline__ float orife_val(
    int idx, const float* __restrict__ x0, const float* __restrict__ x1,
    const float* __restrict__ x2, const float* __restrict__ x3,
    const float* __restrict__ x4)
{
    int p = idx % PP; int bc = idx / PP;
    if (p >= PR) return 0.0f;
    int y = p / GW, x = p % GW;
    const float* p0 = x0 + (size_t)bc * 40000;
    float m0 = NEG_BIG;
    #pragma unroll
    for (int dy = 0; dy < 4; dy++) {
        f32x4 r = *(const f32x4*)(p0 + (y * 4 + dy) * 200 + x * 4);
        m0 = fmaxf(m0, fmaxf(fmaxf(r[0], r[1]), fmaxf(r[2], r[3])));
    }
    const float* p1 = x1 + (size_t)bc * 10000;
    float m1 = fmaxf(fmaxf(p1[(y*2)*100 + x*2],   p1[(y*2)*100 + x*2+1]),
                     fmaxf(p1[(y*2+1)*100 + x*2], p1[(y*2+1)*100 + x*2+1]));
    float v2 = x2[(size_t)bc * 2500 + p];
    float v3 = x3[(size_t)bc * 625 + (y/2)*25 + (x/2)];
    int ry = (y * 13) / 50, rx = (x * 13) / 50;
    float v4 = x4[(size_t)bc * 169 + ry * 13 + rx];
    return (m0 + m1 + v2 + v3 + v4) * 0.2f;
}

// ================= k_pre: rowm | colm | wcvt | ctap | orife =================
// block ranges: [0,388) rowm, [388,395) colm, [395,1419) wcvt,
//               [1419,2254) ctap, [2254,4814) orife(x4 batched)
constexpr int ORIFE_T = 2560 * 256;

__global__ __launch_bounds__(256) void k_pre(
    const float* __restrict__ x0, const float* __restrict__ x1,
    const float* __restrict__ x2, const float* __restrict__ x3,
    const float* __restrict__ x4, const float* __restrict__ rc_w,
    const float* __restrict__ wth, const float* __restrict__ wph,
    const float* __restrict__ wg,  const float* __restrict__ wout,
    unsigned short* __restrict__ wb, float* __restrict__ ori,
    float* __restrict__ z, float* __restrict__ row, float* __restrict__ col)
{
    __shared__ float wsm[C * 12];
    const int bx = blockIdx.x;
    const int tid = threadIdx.x;

    if (bx < 388) {
        // ---- row means: 4 rows/block, one per wave ----
        int rid = bx * 4 + (tid >> 6);
        int lane = tid & 63;
        int base, H; const float* x;
        if      (rid < 800)  { base = 0;    H = 200; x = x0; }
        else if (rid < 1200) { base = 800;  H = 100; x = x1; }
        else if (rid < 1400) { base = 1200; H = 50;  x = x2; }
        else if (rid < 1500) { base = 1400; H = 25;  x = x3; }
        else                 { base = 1500; H = 13;  x = x4; }
        int r = rid - base; int b = r / H, h = r - (r / H) * H;
        const float* xr = x + (size_t)b * C * H * H + (size_t)h * H;
        float s = 0.0f;
        for (int w = lane; w < H; w += 64) s += xr[w];
        #pragma unroll
        for (int off = 32; off > 0; off >>= 1) s += __shfl_down(s, off);
        if (lane == 0) row[rid] = s / (float)H;
    } else if (bx < 395) {
        // ---- col means: thread per (lvl,b,w), 4 load streams ----
        int idx = (bx - 388) * 256 + tid;
        if (idx >= 1552) return;
        int base, H; const float* x;
        if      (idx < 800)  { base = 0;    H = 200; x = x0; }
        else if (idx < 1200) { base = 800;  H = 100; x = x1; }
        else if (idx < 1400) { base = 1200; H = 50;  x = x2; }
        else if (idx < 1500) { base = 1400; H = 25;  x = x3; }
        else                 { base = 1500; H = 13;  x = x4; }
        int r = idx - base; int b = r / H, w = r - (r / H) * H;
        const float* xc = x + (size_t)b * C * H * H + w;
        float s = 0.0f;
        int h = 0;
        for (; h + 3 < H; h += 4) {
            float a0 = xc[(size_t)h * H];
            float a1 = xc[(size_t)(h + 1) * H];
            float a2 = xc[(size_t)(h + 2) * H];
            float a3 = xc[(size_t)(h + 3) * H];
            s += (a0 + a1) + (a2 + a3);
        }
        for (; h < H; h++) s += xc[(size_t)h * H];
        col[idx] = s / (float)H;
    } else if (bx < 1419) {
        // ---- weight convert: 4 x 256x256 ----
        int idx = (bx - 395) * 256 + tid;
        int seg = idx >> 16, off = idx & 65535;
        const float* s = (seg == 0) ? wth : (seg == 1) ? wph : (seg == 2) ? wg : wout;
        wb[idx] = f2b(s[off]);
    } else if (bx < 2254) {
        // ---- conv3x3 pass1: 1 px/thread, 8-wide channel batches ----
        int bxx = bx - 1419;
        int lvl, base, HW, zb; const float* x;
        if      (bxx < 625) { lvl = 0; base = 0;   HW = 40000; zb = 0;      x = x0; }
        else if (bxx < 782) { lvl = 1; base = 625; HW = 10000; zb = 160000; x = x1; }
        else if (bxx < 822) { lvl = 2; base = 782; HW = 2500;  zb = 200000; x = x2; }
        else if (bxx < 832) { lvl = 3; base = 822; HW = 625;   zb = 210000; x = x3; }
        else                { lvl = 4; base = 832; HW = 169;   zb = 212500; x = x4; }

        const float* w9 = rc_w + (size_t)lvl * C * 9;
        for (int i = tid; i < C * 9; i += 256) wsm[(i / 9) * 12 + (i % 9)] = w9[i];
        __syncthreads();

        int idx = (bxx - base) * 256 + tid;
        if (idx >= B * HW) return;
        int b = idx / HW, p = idx - b * HW;

        float acc[9] = {};
        const float* xp = x + (size_t)b * C * HW + p;
        for (int c0 = 0; c0 < C; c0 += 8) {
            float v[8];
            #pragma unroll
            for (int k = 0; k < 8; k++) v[k] = xp[(size_t)(c0 + k) * HW];
            #pragma unroll
            for (int k = 0; k < 8; k++) {
                const float* wc = &wsm[(c0 + k) * 12];
                f32x4 w0 = *(const f32x4*)wc;
                f32x4 w1 = *(const f32x4*)(wc + 4);
                float w8 = wc[8];
                acc[0] += v[k] * w0[0]; acc[1] += v[k] * w0[1];
                acc[2] += v[k] * w0[2]; acc[3] += v[k] * w0[3];
                acc[4] += v[k] * w1[0]; acc[5] += v[k] * w1[1];
                acc[6] += v[k] * w1[2]; acc[7] += v[k] * w1[3];
                acc[8] += v[k] * w8;
            }
        }
        #pragma unroll
        for (int t = 0; t < 9; t++)
            z[(size_t)t * ZT + zb + idx] = acc[t];
    } else {
        // ---- ori_fe gather: 4 outputs/thread, strided (coalesced) ----
        int t0 = (bx - 2254) * 256 + tid;
        #pragma unroll
        for (int k = 0; k < 4; k++) {
            int idx = t0 + k * ORIFE_T;
            ori[idx] = orife_val(idx, x0, x1, x2, x3, x4);
        }
    }
}

// ================= transpose+convert: ori fp32 [b][c][p] -> u16 [b][p][c] =================
__global__ __launch_bounds__(256) void k_tcvt(const float* __restrict__ ori,
                                              unsigned short* __restrict__ ot)
{
    __shared__ unsigned short t[64][66];
    int p0 = blockIdx.x * 64, c0 = blockIdx.y * 64, b = blockIdx.z;
    int pp = threadIdx.x & 63, cb = threadIdx.x >> 6;
    #pragma unroll
    for (int i = 0; i < 16; i++) {
        int cc = cb * 16 + i;
        t[cc][pp] = f2b(ori[((size_t)b * C + c0 + cc) * PP + p0 + pp]);
    }
    __syncthreads();
    int cc2 = threadIdx.x & 63, pb = threadIdx.x >> 6;
    #pragma unroll
    for (int i = 0; i < 16; i++) {
        int pp2 = pb * 16 + i;
        ot[((size_t)b * PP + p0 + pp2) * C + c0 + cc2] = t[cc2][pp2];
    }
}

// ================= merged projections (th, ph, g) =================
constexpr int LDT = 40;

__global__ __launch_bounds__(256) void k_proj(
    const unsigned short* __restrict__ wb, const unsigned short* __restrict__ orit,
    const float* __restrict__ th_b, const float* __restrict__ ph_b,
    const float* __restrict__ g_b,
    unsigned short* __restrict__ tht, unsigned short* __restrict__ pht,
    unsigned short* __restrict__ gb)
{
    __shared__ __align__(16) unsigned short As[128 * LDT];
    __shared__ __align__(16) unsigned short Bs[128 * LDT];

    const int z = blockIdx.z;
    const int b = z / 3, wsel = z - b * 3;
    const bool tp = (wsel < 2);
    const unsigned short* A = tp ? (orit + (size_t)b * CPP) : (wb + 131072);
    const unsigned short* Bm = tp ? (wb + wsel * 65536) : (orit + (size_t)b * CPP);
    const float* bias = (wsel == 0) ? th_b : (wsel == 1) ? ph_b : g_b;

    const int m0 = (tp ? blockIdx.x : blockIdx.y) * 128;
    const int n0 = (tp ? blockIdx.y : blockIdx.x) * 128;
    const int tid = threadIdx.x;
    const int lane = tid & 63, w = tid >> 6;
    const int wm = (w & 1) * 64, wn = (w >> 1) * 64;
    const int fr = lane & 15, fq = lane >> 4;

    f32x4 acc[4][4] = {};
    for (int k0 = 0; k0 < 256; k0 += 32) {
        #pragma unroll
        for (int l = 0; l < 2; l++) {
            int li = tid + l * 256;
            int rr = li >> 2, kc = li & 3;
            short8 va = *(const short8*)(A  + (size_t)(m0 + rr) * 256 + k0 + kc * 8);
            short8 vb = *(const short8*)(Bm + (size_t)(n0 + rr) * 256 + k0 + kc * 8);
            *(short8*)&As[rr * LDT + kc * 8] = va;
            *(short8*)&Bs[rr * LDT + kc * 8] = vb;
        }
        __syncthreads();
        short8 af[4], bf[4];
        #pragma unroll
        for (int i = 0; i < 4; i++)
            af[i] = *(const short8*)&As[(wm + i * 16 + fr) * LDT + fq * 8];
        #pragma unroll
        for (int j = 0; j < 4; j++)
            bf[j] = *(const short8*)&Bs[(wn + j * 16 + fr) * LDT + fq * 8];
        #pragma unroll
        for (int i = 0; i < 4; i++)
            #pragma unroll
            for (int j = 0; j < 4; j++)
                acc[i][j] = __builtin_amdgcn_mfma_f32_16x16x32_bf16(
                    af[i], bf[j], acc[i][j], 0, 0, 0);
        __syncthreads();
    }

    unsigned short* dst = (wsel == 0) ? tht : (wsel == 1) ? pht : gb;
    dst += (size_t)b * CPP;
    #pragma unroll
    for (int i = 0; i < 4; i++) {
        #pragma unroll
        for (int r = 0; r < 4; r++) {
            int gm = m0 + wm + i * 16 + fq * 4 + r;
            #pragma unroll
            for (int j = 0; j < 4; j++) {
                int gn = n0 + wn + j * 16 + fr;
                float v = acc[i][j][r] + (tp ? bias[gn] : bias[gm]);
                size_t off = tp ? ((size_t)gm * 256 + gn) : ((size_t)gm * PP + gn);
                dst[off] = f2b(v);
            }
        }
    }
}

// ================= generic bf16 MFMA GEMM: C = A[M][K] * B[N][K]^T =================
template<bool AddBias, bool AddRes, bool OutBf>
__global__ __launch_bounds__(256) void k_bgemm(
    const unsigned short* __restrict__ A, const unsigned short* __restrict__ Bm,
    const float* __restrict__ bias, const float* __restrict__ res,
    void* __restrict__ Cout, int K, int lda, int ldb, int ldc,
    long long sA, long long sB, long long sC, long long sR,
    int nsplit, long long sK)
{
    __shared__ __align__(16) unsigned short As[128 * LDT];
    __shared__ __align__(16) unsigned short Bs[128 * LDT];

    const int z = blockIdx.z;
    const int bz = z / nsplit, ks = z - bz * nsplit;
    A  += (size_t)sA * bz + (size_t)sK * ks;
    Bm += (size_t)sB * bz + (size_t)sK * ks;

    const int m0 = blockIdx.y * 128, n0 = blockIdx.x * 128;
    const int tid = threadIdx.x;
    const int lane = tid & 63, w = tid >> 6;
    const int wm = (w & 1) * 64, wn = (w >> 1) * 64;
    const int fr = lane & 15, fq = lane >> 4;

    f32x4 acc[4][4] = {};
    for (int k0 = 0; k0 < K; k0 += 32) {
        #pragma unroll
        for (int l = 0; l < 2; l++) {
            int li = tid + l * 256;
            int rr = li >> 2, kc = li & 3;
            short8 va = *(const short8*)(A  + (size_t)(m0 + rr) * lda + k0 + kc * 8);
            short8 vb = *(const short8*)(Bm + (size_t)(n0 + rr) * ldb + k0 + kc * 8);
            *(short8*)&As[rr * LDT + kc * 8] = va;
            *(short8*)&Bs[rr * LDT + kc * 8] = vb;
        }
        __syncthreads();
        short8 af[4], bf[4];
        #pragma unroll
        for (int i = 0; i < 4; i++)
            af[i] = *(const short8*)&As[(wm + i * 16 + fr) * LDT + fq * 8];
        #pragma unroll
        for (int j = 0; j < 4; j++)
            bf[j] = *(const short8*)&Bs[(wn + j * 16 + fr) * LDT + fq * 8];
        #pragma unroll
        for (int i = 0; i < 4; i++)
            #pragma unroll
            for (int j = 0; j < 4; j++)
                acc[i][j] = __builtin_amdgcn_mfma_f32_16x16x32_bf16(
                    af[i], bf[j], acc[i][j], 0, 0, 0);
        __syncthreads();
    }

    float* Cf = (float*)Cout;
    unsigned short* Cb = (unsigned short*)Cout;
    const size_t co = (size_t)sC * z;
    const size_t ro = (size_t)sR * bz;
    #pragma unroll
    for (int i = 0; i < 4; i++) {
        #pragma unroll
        for (int r = 0; r < 4; r++) {
            int gm = m0 + wm + i * 16 + fq * 4 + r;
            #pragma unroll
            for (int j = 0; j < 4; j++) {
                int gn = n0 + wn + j * 16 + fr;
                float v = acc[i][j][r];
                if (AddBias) v += bias[gm];
                if (AddRes)  v += res[ro + (size_t)gm * ldc + gn];
                size_t off = co + (size_t)gm * ldc + gn;
                if (OutBf) Cb[off] = f2b(v);
                else       Cf[off] = v;
            }
        }
    }
}

// ================= yt split-K(2) reduce: fp32 partials -> bf16 ytt =================
__global__ __launch_bounds__(256) void k_ytred(const float* __restrict__ part,
                                               unsigned short* __restrict__ ytt)
{
    int idx = blockIdx.x * 256 + threadIdx.x;
    if (idx >= B * CPP / 4) return;
    int b = idx / (CPP / 4);
    int r = idx - b * (CPP / 4);
    const float* p = part + (size_t)(b * 2) * PS + (size_t)r * 4;
    f32x4 s = *(const f32x4*)p;
    f32x4 q = *(const f32x4*)(p + PS);
    s[0] += q[0]; s[1] += q[1]; s[2] += q[2]; s[3] += q[3];
    u16x4 o;
    #pragma unroll
    for (int k = 0; k < 4; k++) o[k] = f2b(s[k]);
    *(u16x4*)(ytt + (size_t)b * CPP + (size_t)r * 4) = o;
}

// ================= row softmax: bf16 S rows -> bf16 P rows =================
__global__ __launch_bounds__(256) void k_softmax(const unsigned short* __restrict__ S,
                                                 unsigned short* __restrict__ P)
{
    __shared__ float red[256];
    const int row = blockIdx.x;
    const unsigned short* r = S + (size_t)row * PP;
    unsigned short* p = P + (size_t)row * PP;
    const int t = threadIdx.x;
    float v[10];
    float mx = NEG_BIG;
    #pragma unroll
    for (int i = 0; i < 10; i++) {
        int j = i * 256 + t;
        v[i] = (j < PR) ? b2f(r[j]) : NEG_BIG;
        mx = fmaxf(mx, v[i]);
    }
    red[t] = mx; __syncthreads();
    for (int s = 128; s > 0; s >>= 1) { if (t < s) red[t] = fmaxf(red[t], red[t+s]); __syncthreads(); }
    mx = red[0]; __syncthreads();
    float sum = 0.0f;
    #pragma unroll
    for (int i = 0; i < 10; i++) { float e = __expf(v[i] - mx); v[i] = e; sum += e; }
    red[t] = sum; __syncthreads();
    for (int s = 128; s > 0; s >>= 1) { if (t < s) red[t] += red[t+s]; __syncthreads(); }
    float inv = 1.0f / red[0];
    #pragma unroll
    for (int i = 0; i < 10; i++) p[i * 256 + t] = f2b(v[i] * inv);
}

// ================= conv3x3 pass2 fused =================
template<int H, int ZB>
__device__ __forceinline__ void ccomb_impl(int idx, const float* __restrict__ z,
                                           float biasv, float* __restrict__ bas)
{
    constexpr int W = H, HW = H * W;
    int r = idx - ZB; int b = r / HW; int p = r - b * HW;
    int y = p / W, x = p - (p / W) * W;
    float acc = biasv;
    #pragma unroll
    for (int dy = 0; dy < 3; dy++) {
        int yy = y + dy - 1;
        if (yy < 0 || yy >= H) continue;
        #pragma unroll
        for (int dx = 0; dx < 3; dx++) {
            int xx = x + dx - 1;
            if (xx < 0 || xx >= W) continue;
            acc += z[(size_t)(dy * 3 + dx) * ZT + ZB + (size_t)b * HW + yy * W + xx];
        }
    }
    bas[idx] = fmaxf(acc, 0.0f);
}

__global__ __launch_bounds__(256) void k_ccomb_f(const float* __restrict__ z,
                                                 const float* __restrict__ rb,
                                                 float* __restrict__ bas)
{
    int idx = blockIdx.x * 256 + threadIdx.x;
    if (idx >= ZT) return;
    if      (idx < 160000) ccomb_impl<200, 0>     (idx, z, rb[0], bas);
    else if (idx < 200000) ccomb_impl<100, 160000>(idx, z, rb[1], bas);
    else if (idx < 210000) ccomb_impl<50,  200000>(idx, z, rb[2], bas);
    else if (idx < 212500) ccomb_impl<25,  210000>(idx, z, rb[3], bas);
    else                   ccomb_impl<13,  212500>(idx, z, rb[4], bas);
}

// ================= per-sample stats fused (block per (lvl,b)) =================
__global__ __launch_bounds__(256) void k_stats_f(
    const float* __restrict__ row, const float* __restrict__ col,
    const float* __restrict__ basic, float* __restrict__ stats)
{
    const int Ht[5]  = {200, 100, 50, 25, 13};
    const int ZBt[5] = {0, 160000, 200000, 210000, 212500};
    const int RBt[5] = {0, 800, 1200, 1400, 1500};
    int lvl = blockIdx.x >> 2, b = blockIdx.x & 3;
    int H = Ht[lvl], HW = H * H;
    const float* rw = row + RBt[lvl] + b * H;
    const float* cl = col + RBt[lvl] + b * H;
    const float* bb = basic + ZBt[lvl] + (size_t)b * HW;

    __shared__ float smn[256], smx[256];
    int t = threadIdx.x;
    float rmn, rmx, cmn, cmx, bmn, bmx;

    float mn = 3.4e38f, mx = NEG_BIG;
    for (int h = t; h < H; h += 256) { float v = rw[h]; mn = fminf(mn, v); mx = fmaxf(mx, v); }
    smn[t] = mn; smx[t] = mx; __syncthreads();
    for (int s = 128; s > 0; s >>= 1) { if (t < s) { smn[t] = fminf(smn[t], smn[t+s]); smx[t] = fmaxf(smx[t], smx[t+s]); } __syncthreads(); }
    rmn = smn[0]; rmx = smx[0]; __syncthreads();

    mn = 3.4e38f; mx = NEG_BIG;
    for (int w = t; w < H; w += 256) { float v = cl[w]; mn = fminf(mn, v); mx = fmaxf(mx, v); }
    smn[t] = mn; smx[t] = mx; __syncthreads();
    for (int s = 128; s > 0; s >>= 1) { if (t < s) { smn[t] = fminf(smn[t], smn[t+s]); smx[t] = fmaxf(smx[t], smx[t+s]); } __syncthreads(); }
    cmn = smn[0]; cmx = smx[0]; __syncthreads();

    mn = 3.4e38f; mx = NEG_BIG;
    for (int i = t; i < HW; i += 256) { float v = bb[i]; mn = fminf(mn, v); mx = fmaxf(mx, v); }
    smn[t] = mn; smx[t] = mx; __syncthreads();
    for (int s = 128; s > 0; s >>= 1) { if (t < s) { smn[t] = fminf(smn[t], smn[t+s]); smx[t] = fmaxf(smx[t], smx[t+s]); } __syncthreads(); }
    bmn = smn[0]; bmx = smx[0];

    if (t == 0) {
        float p1 = rmn * cmn, p2 = rmn * cmx, p3 = rmx * cmn, p4 = rmx * cmx;
        float amn = fminf(fminf(p1, p2), fminf(p3, p4));
        float amx = fmaxf(fmaxf(p1, p2), fmaxf(p3, p4));
        float* st = stats + lvl * 16 + b * 4;
        st[0] = amn; st[1] = amx; st[2] = bmn; st[3] = bmx;
    }
}

// ================= distance map fused (in-place over basic) =================
template<int H, int ZB, int RB, int LVL>
__device__ __forceinline__ void dist_impl(int idx, float* __restrict__ basic,
                                          const float* __restrict__ row,
                                          const float* __restrict__ col,
                                          const float* __restrict__ stats)
{
    constexpr int HW = H * H;
    int r = idx - ZB; int b = r / HW; int p = r - b * HW;
    int yh = p / H, xw = p - (p / H) * H;
    const float* st = stats + LVL * 16 + b * 4;
    float amn = st[0], amx = st[1], bmn = st[2], bmx = st[3];
    float an = (row[RB + b * H + yh] * col[RB + b * H + xw] - amn) / (amx - amn + EPSV);
    float bn = (basic[idx] - bmn) / (bmx - bmn + EPSV);
    basic[idx] = cosf((an - bn) * PI_2);
}

__global__ __launch_bounds__(256) void k_dist_f(float* __restrict__ basic,
                                                const float* __restrict__ row,
                                                const float* __restrict__ col,
                                                const float* __restrict__ stats)
{
    int idx = blockIdx.x * 256 + threadIdx.x;
    if (idx >= ZT) return;
    if      (idx < 160000) dist_impl<200, 0,      0,    0>(idx, basic, row, col, stats);
    else if (idx < 200000) dist_impl<100, 160000, 800,  1>(idx, basic, row, col, stats);
    else if (idx < 210000) dist_impl<50,  200000, 1200, 2>(idx, basic, row, col, stats);
    else if (idx < 212500) dist_impl<25,  210000, 1400, 3>(idx, basic, row, col, stats);
    else                   dist_impl<13,  212500, 1500, 4>(idx, basic, row, col, stats);
}

// ================= final: out = x + relu(bsf_resized * dist), batched =================
template<int LVL>
__device__ __forceinline__ void final_v4(int vid, const float* __restrict__ x,
                                         const unsigned short* __restrict__ bsf,
                                         const float* __restrict__ dist,
                                         float* __restrict__ out)
{
    constexpr int H = (LVL == 0) ? 200 : 100;
    constexpr int W = H, HW = H * W, Wv = W / 4;
    int xv = vid % Wv; int t = vid / Wv;
    int yh = t % H; t /= H; int c = t % C; int b = t / C;
    f32x4 xw4 = *(const f32x4*)(x + (size_t)vid * 4);
    f32x4 d4  = *(const f32x4*)(dist + (size_t)b * HW + yh * W + xv * 4);
    const unsigned short* bb = bsf + ((size_t)b * C + c) * PP;
    f32x4 o;
    if constexpr (LVL == 0) {
        float bv = b2f(bb[(yh >> 2) * GW + xv]);
        #pragma unroll
        for (int k = 0; k < 4; k++) o[k] = xw4[k] + fmaxf(bv * d4[k], 0.0f);
    } else {
        float bv0 = b2f(bb[(yh >> 1) * GW + 2 * xv]);
        float bv1 = b2f(bb[(yh >> 1) * GW + 2 * xv + 1]);
        o[0] = xw4[0] + fmaxf(bv0 * d4[0], 0.0f);
        o[1] = xw4[1] + fmaxf(bv0 * d4[1], 0.0f);
        o[2] = xw4[2] + fmaxf(bv1 * d4[2], 0.0f);
        o[3] = xw4[3] + fmaxf(bv1 * d4[3], 0.0f);
    }
    *(f32x4*)(out + (size_t)vid * 4) = o;
}

template<int LVL>
__device__ __forceinline__ void final_s(int idx, const float* __restrict__ x,
                                        const unsigned short* __restrict__ bsf,
                                        const float* __restrict__ dist,
                                        float* __restrict__ out)
{
    constexpr int H = (LVL == 2) ? 50 : (LVL == 3) ? 25 : 13;
    constexpr int W = H, HW = H * W;
    int xw = idx % W; int t = idx / W;
    int yh = t % H; t /= H; int c = t % C; int b = t / C;
    float d = dist[(size_t)b * HW + yh * W + xw];
    constexpr bool ident = (LVL == 2);
    int ry = ident ? yh : (yh * GW) / H;
    int rx = ident ? xw : (xw * GW) / W;
    float bv = b2f(bsf[((size_t)b * C + c) * PP + ry * GW + rx]);
    out[idx] = x[idx] + fmaxf(bv * d, 0.0f);
}

__global__ __launch_bounds__(256) void k_final_f(
    const float* __restrict__ x0, const float* __restrict__ x1,
    const float* __restrict__ x2, const float* __restrict__ x3,
    const float* __restrict__ x4, const unsigned short* __restrict__ bsf,
    const float* __restrict__ basic, float* __restrict__ out)
{
    int bx = blockIdx.x;
    int tid = threadIdx.x;
    if (bx < 8000) {
        int t0 = bx * 256 + tid;
        #pragma unroll
        for (int k = 0; k < 5; k++)
            final_v4<0>(t0 + k * 2048000, x0, bsf, basic, out);
    } else if (bx < 10000) {
        int t0 = (bx - 8000) * 256 + tid;
        #pragma unroll
        for (int k = 0; k < 5; k++)
            final_v4<1>(t0 + k * 512000, x1, bsf, basic + 160000, out + 40960000ull);
    } else if (bx < 12000) {
        int t0 = (bx - 10000) * 256 + tid;
        #pragma unroll
        for (int k = 0; k < 5; k++)
            final_s<2>(t0 + k * 512000, x2, bsf, basic + 200000, out + 51200000ull);
    } else if (bx < 12500) {
        int t0 = (bx - 12000) * 256 + tid;
        #pragma unroll
        for (int k = 0; k < 5; k++)
            final_s<3>(t0 + k * 128000, x3, bsf, basic + 210000, out + 53760000ull);
    } else {
        int t0 = (bx - 12500) * 256 + tid;
        #pragma unroll
        for (int k = 0; k < 4; k++)
            final_s<4>(t0 + k * 43264, x4, bsf, basic + 212500, out + 54400000ull);
    }
}

// ================= host =================
extern "C" void kernel_launch(void* const* d_in, const int* in_sizes, int n_in,
                              void* d_out, int out_size, void* d_ws, size_t ws_size,
                              hipStream_t stream)
{
    const float* x[5]; for (int i = 0; i < 5; i++) x[i] = (const float*)d_in[i];
    const float* rc_w  = (const float*)d_in[5];
    const float* rc_b  = (const float*)d_in[6];
    const float* g_b   = (const float*)d_in[8];
    const float* th_b  = (const float*)d_in[10];
    const float* ph_b  = (const float*)d_in[12];
    const float* out_b = (const float*)d_in[14];
    float* out = (float*)d_out;

    float* ws    = (float*)d_ws;
    float* ori   = ws + OFF_ORI;
    unsigned short* bsf = (unsigned short*)(ws + OFF_BSF);   // bf16 bsf
    float* zbuf  = ws + OFF_Z;
    float* basic = ws + OFF_BASIC;
    float* rowb  = ws + OFF_ROW;
    float* colb  = ws + OFF_COL;
    float* stats = ws + OFF_STATS;
    unsigned short* u16 = (unsigned short*)(ws + OFF_U16);
    unsigned short* orit = u16 + U_ORIT;
    unsigned short* tht  = u16 + U_THT;
    unsigned short* pht  = u16 + U_PHT;
    unsigned short* gb   = u16 + U_G;
    unsigned short* ytt  = u16 + U_YTT;
    unsigned short* wb   = u16 + U_WB;
    unsigned short* wb_out = wb + 196608;

    // scratch in d_out (fully consumed before k_final_f writes)
    unsigned short* S_all = (unsigned short*)out;            // u16 [4][2560][2560]
    unsigned short* P_all = S_all + 4 * SPB;                 // u16 [4][2560][2560]
    float* part = out + 4 * SPB;                             // fp32 [8][2560][256]

    // 1) pre: rowm + colm + wcvt + ctap + orife (one launch)
    k_pre<<<4814, 256, 0, stream>>>(
        x[0], x[1], x[2], x[3], x[4], rc_w,
        (const float*)d_in[9], (const float*)d_in[11],
        (const float*)d_in[7], (const float*)d_in[13],
        wb, ori, zbuf, rowb, colb);

    // 2) ori transpose+convert
    k_tcvt<<<dim3(PP / 64, C / 64, B), 256, 0, stream>>>(ori, orit);

    // 3) merged projections th/ph/g (z = b*3 + wsel)
    k_proj<<<dim3(20, 2, 12), 256, 0, stream>>>(wb, orit, th_b, ph_b, g_b, tht, pht, gb);

    // small per-level chain (independent of attention)
    k_ccomb_f<<<(ZT + 255) / 256, 256, 0, stream>>>(zbuf, rc_b, basic);
    k_stats_f<<<20, 256, 0, stream>>>(rowb, colb, basic, stats);
    k_dist_f<<<(ZT + 255) / 256, 256, 0, stream>>>(basic, rowb, colb, stats);

    // 4) S = tht @ pht^T  (bf16 out, in d_out)
    dim3 gsc(PP / 128, PP / 128, B);
    k_bgemm<false, false, true><<<gsc, 256, 0, stream>>>(
        tht, pht, nullptr, nullptr, S_all, C, C, C, PP, CPP, CPP, SPB, 0, 1, 0);

    // 5) softmax rows -> P
    k_softmax<<<B * PP, 256, 0, stream>>>(S_all, P_all);

    // 6) yt = P @ g^T, split-K x2, fp32 partials; then reduce -> ytt [p][c]
    dim3 gyt(C / 128, PP / 128, B * 2);
    k_bgemm<false, false, false><<<gyt, 256, 0, stream>>>(
        P_all, gb, nullptr, nullptr, part, PP / 2, PP, PP, C, SPB, CPP, PS, 0, 2, PP / 2);
    k_ytred<<<(B * CPP / 4 + 255) / 256, 256, 0, stream>>>(part, ytt);

    // 7) bsf = out_w @ yt + out_b + ori  (bf16 out)
    dim3 gbsf(PP / 128, C / 128, B);
    k_bgemm<true, true, true><<<gbsf, 256, 0, stream>>>(
        wb_out, ytt, out_b, ori, bsf, C, C, C, PP, 0, CPP, CPP, CPP, 1, 0);

    // 8) finals (one launch, all levels, 5x/4x batched)
    k_final_f<<<12669, 256, 0, stream>>>(
        x[0], x[1], x[2], x[3], x[4], bsf, basic, out);
}

// Round 8
// 334.852 us; speedup vs baseline: 1.2464x; 1.0382x over previous
//
#include <hip/hip_runtime.h>
#include <math.h>

typedef __attribute__((ext_vector_type(8))) short short8;
typedef __attribute__((ext_vector_type(4))) float f32x4;
typedef __attribute__((ext_vector_type(4))) unsigned short u16x4;

#define EPSV 1e-7f
#define PI_2 1.57079632679489662f
#define NEG_BIG (-3.4e38f)

constexpr int B = 4, C = 256;
constexpr int GW = 50;
constexpr int PR = 2500, PP = 2560;              // real / padded 50x50
constexpr int CPP = C * PP;                      // 655,360
constexpr long long SPB = (long long)PP * PP;    // 6,553,600
constexpr int PS = PP * C;                       // partial slice
constexpr int ZT = 213176;                       // sum_l B*H_l*W_l

// ---- workspace float offsets ----
constexpr size_t OFF_ORI   = 0;                            // fp32 [4][256][2560]
constexpr size_t OFF_BSF   = OFF_ORI + (size_t)B * CPP;    // u16 [4][256][2560] (bf16 bsf)
constexpr size_t OFF_Z     = OFF_BSF + (size_t)B * CPP;    // fp32 [9][ZT]
constexpr size_t OFF_BASIC = OFF_Z + (size_t)9 * ZT;
constexpr size_t OFF_ROW   = OFF_BASIC + 213184;
constexpr size_t OFF_COL   = OFF_ROW + 1600;
constexpr size_t OFF_STATS = OFF_COL + 1600;
constexpr size_t OFF_RSUM  = OFF_STATS + 128;              // fp32 [4][2560] softmax denoms
constexpr size_t OFF_U16   = OFF_RSUM + 10240;
// ---- u16 offsets within u16 region ----
constexpr size_t U_ORIT = 0;                               // [4][2560][256]
constexpr size_t U_THT  = U_ORIT + (size_t)B * CPP;
constexpr size_t U_PHT  = U_THT  + (size_t)B * CPP;
constexpr size_t U_G    = U_PHT  + (size_t)B * CPP;        // [4][256][2560]
constexpr size_t U_YTT  = U_G    + (size_t)B * CPP;        // [4][2560][256]
constexpr size_t U_WB   = U_YTT  + (size_t)B * CPP;        // 4 x [256][256]

__device__ __forceinline__ unsigned short f2b(float x) {
    union { float f; unsigned u; } q{x};
    unsigned r = q.u + 0x7FFFu + ((q.u >> 16) & 1u);
    return (unsigned short)(r >> 16);
}
__device__ __forceinline__ float b2f(unsigned short u) {
    union { unsigned u; float f; } q{(unsigned)u << 16};
    return q.f;
}

// ---- ori_fe single-element body ----
__device__ __forceinline__ float orife_val(
    int idx, const float* __restrict__ x0, const float* __restrict__ x1,
    const float* __restrict__ x2, const float* __restrict__ x3,
    const float* __restrict__ x4)
{
    int p = idx % PP; int bc = idx / PP;
    if (p >= PR) return 0.0f;
    int y = p / GW, x = p % GW;
    const float* p0 = x0 + (size_t)bc * 40000;
    float m0 = NEG_BIG;
    #pragma unroll
    for (int dy = 0; dy < 4; dy++) {
        f32x4 r = *(const f32x4*)(p0 + (y * 4 + dy) * 200 + x * 4);
        m0 = fmaxf(m0, fmaxf(fmaxf(r[0], r[1]), fmaxf(r[2], r[3])));
    }
    const float* p1 = x1 + (size_t)bc * 10000;
    float m1 = fmaxf(fmaxf(p1[(y*2)*100 + x*2],   p1[(y*2)*100 + x*2+1]),
                     fmaxf(p1[(y*2+1)*100 + x*2], p1[(y*2+1)*100 + x*2+1]));
    float v2 = x2[(size_t)bc * 2500 + p];
    float v3 = x3[(size_t)bc * 625 + (y/2)*25 + (x/2)];
    int ry = (y * 13) / 50, rx = (x * 13) / 50;
    float v4 = x4[(size_t)bc * 169 + ry * 13 + rx];
    return (m0 + m1 + v2 + v3 + v4) * 0.2f;
}

// ================= k_pre: rowm | colm | wcvt | ctap | orife | rsum-zero =================
// block ranges: [0,388) rowm, [388,395) colm, [395,1419) wcvt,
//               [1419,2254) ctap, [2254,4814) orife(x4), [4814,4824) rsum zero
constexpr int ORIFE_T = 2560 * 256;

__global__ __launch_bounds__(256) void k_pre(
    const float* __restrict__ x0, const float* __restrict__ x1,
    const float* __restrict__ x2, const float* __restrict__ x3,
    const float* __restrict__ x4, const float* __restrict__ rc_w,
    const float* __restrict__ wth, const float* __restrict__ wph,
    const float* __restrict__ wg,  const float* __restrict__ wout,
    unsigned short* __restrict__ wb, float* __restrict__ ori,
    float* __restrict__ z, float* __restrict__ row, float* __restrict__ col,
    float* __restrict__ rowsum)
{
    __shared__ float wsm[C * 12];
    const int bx = blockIdx.x;
    const int tid = threadIdx.x;

    if (bx < 388) {
        // ---- row means: 4 rows/block, one per wave ----
        int rid = bx * 4 + (tid >> 6);
        int lane = tid & 63;
        int base, H; const float* x;
        if      (rid < 800)  { base = 0;    H = 200; x = x0; }
        else if (rid < 1200) { base = 800;  H = 100; x = x1; }
        else if (rid < 1400) { base = 1200; H = 50;  x = x2; }
        else if (rid < 1500) { base = 1400; H = 25;  x = x3; }
        else                 { base = 1500; H = 13;  x = x4; }
        int r = rid - base; int b = r / H, h = r - (r / H) * H;
        const float* xr = x + (size_t)b * C * H * H + (size_t)h * H;
        float s = 0.0f;
        for (int w = lane; w < H; w += 64) s += xr[w];
        #pragma unroll
        for (int off = 32; off > 0; off >>= 1) s += __shfl_down(s, off);
        if (lane == 0) row[rid] = s / (float)H;
    } else if (bx < 395) {
        // ---- col means: thread per (lvl,b,w), 4 load streams ----
        int idx = (bx - 388) * 256 + tid;
        if (idx >= 1552) return;
        int base, H; const float* x;
        if      (idx < 800)  { base = 0;    H = 200; x = x0; }
        else if (idx < 1200) { base = 800;  H = 100; x = x1; }
        else if (idx < 1400) { base = 1200; H = 50;  x = x2; }
        else if (idx < 1500) { base = 1400; H = 25;  x = x3; }
        else                 { base = 1500; H = 13;  x = x4; }
        int r = idx - base; int b = r / H, w = r - (r / H) * H;
        const float* xc = x + (size_t)b * C * H * H + w;
        float s = 0.0f;
        int h = 0;
        for (; h + 3 < H; h += 4) {
            float a0 = xc[(size_t)h * H];
            float a1 = xc[(size_t)(h + 1) * H];
            float a2 = xc[(size_t)(h + 2) * H];
            float a3 = xc[(size_t)(h + 3) * H];
            s += (a0 + a1) + (a2 + a3);
        }
        for (; h < H; h++) s += xc[(size_t)h * H];
        col[idx] = s / (float)H;
    } else if (bx < 1419) {
        // ---- weight convert: 4 x 256x256 ----
        int idx = (bx - 395) * 256 + tid;
        int seg = idx >> 16, off = idx & 65535;
        const float* s = (seg == 0) ? wth : (seg == 1) ? wph : (seg == 2) ? wg : wout;
        wb[idx] = f2b(s[off]);
    } else if (bx < 2254) {
        // ---- conv3x3 pass1: 1 px/thread, 8-wide channel batches ----
        int bxx = bx - 1419;
        int lvl, base, HW, zb; const float* x;
        if      (bxx < 625) { lvl = 0; base = 0;   HW = 40000; zb = 0;      x = x0; }
        else if (bxx < 782) { lvl = 1; base = 625; HW = 10000; zb = 160000; x = x1; }
        else if (bxx < 822) { lvl = 2; base = 782; HW = 2500;  zb = 200000; x = x2; }
        else if (bxx < 832) { lvl = 3; base = 822; HW = 625;   zb = 210000; x = x3; }
        else                { lvl = 4; base = 832; HW = 169;   zb = 212500; x = x4; }

        const float* w9 = rc_w + (size_t)lvl * C * 9;
        for (int i = tid; i < C * 9; i += 256) wsm[(i / 9) * 12 + (i % 9)] = w9[i];
        __syncthreads();

        int idx = (bxx - base) * 256 + tid;
        if (idx >= B * HW) return;
        int b = idx / HW, p = idx - b * HW;

        float acc[9] = {};
        const float* xp = x + (size_t)b * C * HW + p;
        for (int c0 = 0; c0 < C; c0 += 8) {
            float v[8];
            #pragma unroll
            for (int k = 0; k < 8; k++) v[k] = xp[(size_t)(c0 + k) * HW];
            #pragma unroll
            for (int k = 0; k < 8; k++) {
                const float* wc = &wsm[(c0 + k) * 12];
                f32x4 w0 = *(const f32x4*)wc;
                f32x4 w1 = *(const f32x4*)(wc + 4);
                float w8 = wc[8];
                acc[0] += v[k] * w0[0]; acc[1] += v[k] * w0[1];
                acc[2] += v[k] * w0[2]; acc[3] += v[k] * w0[3];
                acc[4] += v[k] * w1[0]; acc[5] += v[k] * w1[1];
                acc[6] += v[k] * w1[2]; acc[7] += v[k] * w1[3];
                acc[8] += v[k] * w8;
            }
        }
        #pragma unroll
        for (int t = 0; t < 9; t++)
            z[(size_t)t * ZT + zb + idx] = acc[t];
    } else if (bx < 4814) {
        // ---- ori_fe gather: 4 outputs/thread, strided (coalesced) ----
        int t0 = (bx - 2254) * 256 + tid;
        #pragma unroll
        for (int k = 0; k < 4; k++) {
            int idx = t0 + k * ORIFE_T;
            ori[idx] = orife_val(idx, x0, x1, x2, x3, x4);
        }
    } else {
        // ---- zero rowsum ----
        int idx = (bx - 4814) * 1024 + tid * 4;
        f32x4 zv = {0.0f, 0.0f, 0.0f, 0.0f};
        *(f32x4*)(rowsum + idx) = zv;
    }
}

// ================= transpose+convert: ori fp32 [b][c][p] -> u16 [b][p][c] =================
__global__ __launch_bounds__(256) void k_tcvt(const float* __restrict__ ori,
                                              unsigned short* __restrict__ ot)
{
    __shared__ unsigned short t[64][66];
    int p0 = blockIdx.x * 64, c0 = blockIdx.y * 64, b = blockIdx.z;
    int pp = threadIdx.x & 63, cb = threadIdx.x >> 6;
    #pragma unroll
    for (int i = 0; i < 16; i++) {
        int cc = cb * 16 + i;
        t[cc][pp] = f2b(ori[((size_t)b * C + c0 + cc) * PP + p0 + pp]);
    }
    __syncthreads();
    int cc2 = threadIdx.x & 63, pb = threadIdx.x >> 6;
    #pragma unroll
    for (int i = 0; i < 16; i++) {
        int pp2 = pb * 16 + i;
        ot[((size_t)b * PP + p0 + pp2) * C + c0 + cc2] = t[cc2][pp2];
    }
}

// ================= merged projections (th, ph, g) =================
constexpr int LDT = 40;

__global__ __launch_bounds__(256) void k_proj(
    const unsigned short* __restrict__ wb, const unsigned short* __restrict__ orit,
    const float* __restrict__ th_b, const float* __restrict__ ph_b,
    const float* __restrict__ g_b,
    unsigned short* __restrict__ tht, unsigned short* __restrict__ pht,
    unsigned short* __restrict__ gb)
{
    __shared__ __align__(16) unsigned short As[128 * LDT];
    __shared__ __align__(16) unsigned short Bs[128 * LDT];

    const int z = blockIdx.z;
    const int b = z / 3, wsel = z - b * 3;
    const bool tp = (wsel < 2);
    const unsigned short* A = tp ? (orit + (size_t)b * CPP) : (wb + 131072);
    const unsigned short* Bm = tp ? (wb + wsel * 65536) : (orit + (size_t)b * CPP);
    const float* bias = (wsel == 0) ? th_b : (wsel == 1) ? ph_b : g_b;

    const int m0 = (tp ? blockIdx.x : blockIdx.y) * 128;
    const int n0 = (tp ? blockIdx.y : blockIdx.x) * 128;
    const int tid = threadIdx.x;
    const int lane = tid & 63, w = tid >> 6;
    const int wm = (w & 1) * 64, wn = (w >> 1) * 64;
    const int fr = lane & 15, fq = lane >> 4;

    f32x4 acc[4][4] = {};
    for (int k0 = 0; k0 < 256; k0 += 32) {
        #pragma unroll
        for (int l = 0; l < 2; l++) {
            int li = tid + l * 256;
            int rr = li >> 2, kc = li & 3;
            short8 va = *(const short8*)(A  + (size_t)(m0 + rr) * 256 + k0 + kc * 8);
            short8 vb = *(const short8*)(Bm + (size_t)(n0 + rr) * 256 + k0 + kc * 8);
            *(short8*)&As[rr * LDT + kc * 8] = va;
            *(short8*)&Bs[rr * LDT + kc * 8] = vb;
        }
        __syncthreads();
        short8 af[4], bf[4];
        #pragma unroll
        for (int i = 0; i < 4; i++)
            af[i] = *(const short8*)&As[(wm + i * 16 + fr) * LDT + fq * 8];
        #pragma unroll
        for (int j = 0; j < 4; j++)
            bf[j] = *(const short8*)&Bs[(wn + j * 16 + fr) * LDT + fq * 8];
        #pragma unroll
        for (int i = 0; i < 4; i++)
            #pragma unroll
            for (int j = 0; j < 4; j++)
                acc[i][j] = __builtin_amdgcn_mfma_f32_16x16x32_bf16(
                    af[i], bf[j], acc[i][j], 0, 0, 0);
        __syncthreads();
    }

    unsigned short* dst = (wsel == 0) ? tht : (wsel == 1) ? pht : gb;
    dst += (size_t)b * CPP;
    #pragma unroll
    for (int i = 0; i < 4; i++) {
        #pragma unroll
        for (int r = 0; r < 4; r++) {
            int gm = m0 + wm + i * 16 + fq * 4 + r;
            #pragma unroll
            for (int j = 0; j < 4; j++) {
                int gn = n0 + wn + j * 16 + fr;
                float v = acc[i][j][r] + (tp ? bias[gn] : bias[gm]);
                if (!tp && gn >= PR) v = 0.0f;   // zero g pads (exp-softmax needs it)
                size_t off = tp ? ((size_t)gm * 256 + gn) : ((size_t)gm * PP + gn);
                dst[off] = f2b(v);
            }
        }
    }
}

// ================= generic bf16 MFMA GEMM: C = A[M][K] * B[N][K]^T =================
// AExp: apply exp() to A values during staging; blocks with blockIdx.x==0 also
//       accumulate per-row sums of exp over real columns (<PR) into rowsum.
template<bool AddBias, bool AddRes, bool OutBf, bool AExp>
__global__ __launch_bounds__(256) void k_bgemm(
    const unsigned short* __restrict__ A, const unsigned short* __restrict__ Bm,
    const float* __restrict__ bias, const float* __restrict__ res,
    void* __restrict__ Cout, int K, int lda, int ldb, int ldc,
    long long sA, long long sB, long long sC, long long sR,
    int nsplit, long long sK, float* __restrict__ rowsum)
{
    __shared__ __align__(16) unsigned short As[128 * LDT];
    __shared__ __align__(16) unsigned short Bs[128 * LDT];

    const int z = blockIdx.z;
    const int bz = z / nsplit, ks = z - bz * nsplit;
    A  += (size_t)sA * bz + (size_t)sK * ks;
    Bm += (size_t)sB * bz + (size_t)sK * ks;
    const long long kofs = (long long)sK * ks;

    const int m0 = blockIdx.y * 128, n0 = blockIdx.x * 128;
    const int tid = threadIdx.x;
    const int lane = tid & 63, w = tid >> 6;
    const int wm = (w & 1) * 64, wn = (w >> 1) * 64;
    const int fr = lane & 15, fq = lane >> 4;

    const bool dosum = AExp && (blockIdx.x == 0);
    float rs[2] = {0.0f, 0.0f};

    f32x4 acc[4][4] = {};
    for (int k0 = 0; k0 < K; k0 += 32) {
        #pragma unroll
        for (int l = 0; l < 2; l++) {
            int li = tid + l * 256;
            int rr = li >> 2, kc = li & 3;
            short8 va = *(const short8*)(A  + (size_t)(m0 + rr) * lda + k0 + kc * 8);
            if constexpr (AExp) {
                long long cb = kofs + k0 + kc * 8;
                float ssum = 0.0f;
                #pragma unroll
                for (int e = 0; e < 8; e++) {
                    float f = __expf(b2f((unsigned short)va[e]));
                    if (cb + e < PR) ssum += f;
                    va[e] = (short)f2b(f);
                }
                if (dosum) rs[l] += ssum;
            }
            short8 vb = *(const short8*)(Bm + (size_t)(n0 + rr) * ldb + k0 + kc * 8);
            *(short8*)&As[rr * LDT + kc * 8] = va;
            *(short8*)&Bs[rr * LDT + kc * 8] = vb;
        }
        __syncthreads();
        short8 af[4], bf[4];
        #pragma unroll
        for (int i = 0; i < 4; i++)
            af[i] = *(const short8*)&As[(wm + i * 16 + fr) * LDT + fq * 8];
        #pragma unroll
        for (int j = 0; j < 4; j++)
            bf[j] = *(const short8*)&Bs[(wn + j * 16 + fr) * LDT + fq * 8];
        #pragma unroll
        for (int i = 0; i < 4; i++)
            #pragma unroll
            for (int j = 0; j < 4; j++)
                acc[i][j] = __builtin_amdgcn_mfma_f32_16x16x32_bf16(
                    af[i], bf[j], acc[i][j], 0, 0, 0);
        __syncthreads();
    }

    if constexpr (AExp) {
        if (dosum) {
            #pragma unroll
            for (int l = 0; l < 2; l++) {
                float s = rs[l];
                s += __shfl_xor(s, 1);
                s += __shfl_xor(s, 2);
                if ((tid & 3) == 0) {
                    int row = (tid >> 2) + l * 64;
                    atomicAdd(&rowsum[(size_t)bz * PP + m0 + row], s);
                }
            }
        }
    }

    float* Cf = (float*)Cout;
    unsigned short* Cb = (unsigned short*)Cout;
    const size_t co = (size_t)sC * z;
    const size_t ro = (size_t)sR * bz;
    #pragma unroll
    for (int i = 0; i < 4; i++) {
        #pragma unroll
        for (int r = 0; r < 4; r++) {
            int gm = m0 + wm + i * 16 + fq * 4 + r;
            #pragma unroll
            for (int j = 0; j < 4; j++) {
                int gn = n0 + wn + j * 16 + fr;
                float v = acc[i][j][r];
                if (AddBias) v += bias[gm];
                if (AddRes)  v += res[ro + (size_t)gm * ldc + gn];
                size_t off = co + (size_t)gm * ldc + gn;
                if (OutBf) Cb[off] = f2b(v);
                else       Cf[off] = v;
            }
        }
    }
}

// ================= yt split-K(2) reduce + softmax normalize -> bf16 ytt =================
__global__ __launch_bounds__(256) void k_ytred(const float* __restrict__ part,
                                               const float* __restrict__ rowsum,
                                               unsigned short* __restrict__ ytt)
{
    int idx = blockIdx.x * 256 + threadIdx.x;
    if (idx >= B * CPP / 4) return;
    int b = idx / (CPP / 4);
    int r = idx - b * (CPP / 4);
    const float* p = part + (size_t)(b * 2) * PS + (size_t)r * 4;
    f32x4 s = *(const f32x4*)p;
    f32x4 q = *(const f32x4*)(p + PS);
    int p_row = r >> 6;                     // r / (C/4)
    float inv = 1.0f / rowsum[(size_t)b * PP + p_row];
    u16x4 o;
    #pragma unroll
    for (int k = 0; k < 4; k++) o[k] = f2b((s[k] + q[k]) * inv);
    *(u16x4*)(ytt + (size_t)b * CPP + (size_t)r * 4) = o;
}

// ================= conv3x3 pass2 fused =================
template<int H, int ZB>
__device__ __forceinline__ void ccomb_impl(int idx, const float* __restrict__ z,
                                           float biasv, float* __restrict__ bas)
{
    constexpr int W = H, HW = H * W;
    int r = idx - ZB; int b = r / HW; int p = r - b * HW;
    int y = p / W, x = p - (p / W) * W;
    float acc = biasv;
    #pragma unroll
    for (int dy = 0; dy < 3; dy++) {
        int yy = y + dy - 1;
        if (yy < 0 || yy >= H) continue;
        #pragma unroll
        for (int dx = 0; dx < 3; dx++) {
            int xx = x + dx - 1;
            if (xx < 0 || xx >= W) continue;
            acc += z[(size_t)(dy * 3 + dx) * ZT + ZB + (size_t)b * HW + yy * W + xx];
        }
    }
    bas[idx] = fmaxf(acc, 0.0f);
}

__global__ __launch_bounds__(256) void k_ccomb_f(const float* __restrict__ z,
                                                 const float* __restrict__ rb,
                                                 float* __restrict__ bas)
{
    int idx = blockIdx.x * 256 + threadIdx.x;
    if (idx >= ZT) return;
    if      (idx < 160000) ccomb_impl<200, 0>     (idx, z, rb[0], bas);
    else if (idx < 200000) ccomb_impl<100, 160000>(idx, z, rb[1], bas);
    else if (idx < 210000) ccomb_impl<50,  200000>(idx, z, rb[2], bas);
    else if (idx < 212500) ccomb_impl<25,  210000>(idx, z, rb[3], bas);
    else                   ccomb_impl<13,  212500>(idx, z, rb[4], bas);
}

// ================= per-sample stats fused (block per (lvl,b)) =================
__global__ __launch_bounds__(256) void k_stats_f(
    const float* __restrict__ row, const float* __restrict__ col,
    const float* __restrict__ basic, float* __restrict__ stats)
{
    const int Ht[5]  = {200, 100, 50, 25, 13};
    const int ZBt[5] = {0, 160000, 200000, 210000, 212500};
    const int RBt[5] = {0, 800, 1200, 1400, 1500};
    int lvl = blockIdx.x >> 2, b = blockIdx.x & 3;
    int H = Ht[lvl], HW = H * H;
    const float* rw = row + RBt[lvl] + b * H;
    const float* cl = col + RBt[lvl] + b * H;
    const float* bb = basic + ZBt[lvl] + (size_t)b * HW;

    __shared__ float smn[256], smx[256];
    int t = threadIdx.x;
    float rmn, rmx, cmn, cmx, bmn, bmx;

    float mn = 3.4e38f, mx = NEG_BIG;
    for (int h = t; h < H; h += 256) { float v = rw[h]; mn = fminf(mn, v); mx = fmaxf(mx, v); }
    smn[t] = mn; smx[t] = mx; __syncthreads();
    for (int s = 128; s > 0; s >>= 1) { if (t < s) { smn[t] = fminf(smn[t], smn[t+s]); smx[t] = fmaxf(smx[t], smx[t+s]); } __syncthreads(); }
    rmn = smn[0]; rmx = smx[0]; __syncthreads();

    mn = 3.4e38f; mx = NEG_BIG;
    for (int w = t; w < H; w += 256) { float v = cl[w]; mn = fminf(mn, v); mx = fmaxf(mx, v); }
    smn[t] = mn; smx[t] = mx; __syncthreads();
    for (int s = 128; s > 0; s >>= 1) { if (t < s) { smn[t] = fminf(smn[t], smn[t+s]); smx[t] = fmaxf(smx[t], smx[t+s]); } __syncthreads(); }
    cmn = smn[0]; cmx = smx[0]; __syncthreads();

    mn = 3.4e38f; mx = NEG_BIG;
    for (int i = t; i < HW; i += 256) { float v = bb[i]; mn = fminf(mn, v); mx = fmaxf(mx, v); }
    smn[t] = mn; smx[t] = mx; __syncthreads();
    for (int s = 128; s > 0; s >>= 1) { if (t < s) { smn[t] = fminf(smn[t], smn[t+s]); smx[t] = fmaxf(smx[t], smx[t+s]); } __syncthreads(); }
    bmn = smn[0]; bmx = smx[0];

    if (t == 0) {
        float p1 = rmn * cmn, p2 = rmn * cmx, p3 = rmx * cmn, p4 = rmx * cmx;
        float amn = fminf(fminf(p1, p2), fminf(p3, p4));
        float amx = fmaxf(fmaxf(p1, p2), fmaxf(p3, p4));
        float* st = stats + lvl * 16 + b * 4;
        st[0] = amn; st[1] = amx; st[2] = bmn; st[3] = bmx;
    }
}

// ================= distance map fused (in-place over basic) =================
template<int H, int ZB, int RB, int LVL>
__device__ __forceinline__ void dist_impl(int idx, float* __restrict__ basic,
                                          const float* __restrict__ row,
                                          const float* __restrict__ col,
                                          const float* __restrict__ stats)
{
    constexpr int HW = H * H;
    int r = idx - ZB; int b = r / HW; int p = r - b * HW;
    int yh = p / H, xw = p - (p / H) * H;
    const float* st = stats + LVL * 16 + b * 4;
    float amn = st[0], amx = st[1], bmn = st[2], bmx = st[3];
    float an = (row[RB + b * H + yh] * col[RB + b * H + xw] - amn) / (amx - amn + EPSV);
    float bn = (basic[idx] - bmn) / (bmx - bmn + EPSV);
    basic[idx] = cosf((an - bn) * PI_2);
}

__global__ __launch_bounds__(256) void k_dist_f(float* __restrict__ basic,
                                                const float* __restrict__ row,
                                                const float* __restrict__ col,
                                                const float* __restrict__ stats)
{
    int idx = blockIdx.x * 256 + threadIdx.x;
    if (idx >= ZT) return;
    if      (idx < 160000) dist_impl<200, 0,      0,    0>(idx, basic, row, col, stats);
    else if (idx < 200000) dist_impl<100, 160000, 800,  1>(idx, basic, row, col, stats);
    else if (idx < 210000) dist_impl<50,  200000, 1200, 2>(idx, basic, row, col, stats);
    else if (idx < 212500) dist_impl<25,  210000, 1400, 3>(idx, basic, row, col, stats);
    else                   dist_impl<13,  212500, 1500, 4>(idx, basic, row, col, stats);
}

// ================= final: out = x + relu(bsf_resized * dist), batched =================
template<int LVL>
__device__ __forceinline__ void final_v4(int vid, const float* __restrict__ x,
                                         const unsigned short* __restrict__ bsf,
                                         const float* __restrict__ dist,
                                         float* __restrict__ out)
{
    constexpr int H = (LVL == 0) ? 200 : 100;
    constexpr int W = H, HW = H * W, Wv = W / 4;
    int xv = vid % Wv; int t = vid / Wv;
    int yh = t % H; t /= H; int c = t % C; int b = t / C;
    f32x4 xw4 = *(const f32x4*)(x + (size_t)vid * 4);
    f32x4 d4  = *(const f32x4*)(dist + (size_t)b * HW + yh * W + xv * 4);
    const unsigned short* bb = bsf + ((size_t)b * C + c) * PP;
    f32x4 o;
    if constexpr (LVL == 0) {
        float bv = b2f(bb[(yh >> 2) * GW + xv]);
        #pragma unroll
        for (int k = 0; k < 4; k++) o[k] = xw4[k] + fmaxf(bv * d4[k], 0.0f);
    } else {
        float bv0 = b2f(bb[(yh >> 1) * GW + 2 * xv]);
        float bv1 = b2f(bb[(yh >> 1) * GW + 2 * xv + 1]);
        o[0] = xw4[0] + fmaxf(bv0 * d4[0], 0.0f);
        o[1] = xw4[1] + fmaxf(bv0 * d4[1], 0.0f);
        o[2] = xw4[2] + fmaxf(bv1 * d4[2], 0.0f);
        o[3] = xw4[3] + fmaxf(bv1 * d4[3], 0.0f);
    }
    *(f32x4*)(out + (size_t)vid * 4) = o;
}

template<int LVL>
__device__ __forceinline__ void final_s(int idx, const float* __restrict__ x,
                                        const unsigned short* __restrict__ bsf,
                                        const float* __restrict__ dist,
                                        float* __restrict__ out)
{
    constexpr int H = (LVL == 2) ? 50 : (LVL == 3) ? 25 : 13;
    constexpr int W = H, HW = H * W;
    int xw = idx % W; int t = idx / W;
    int yh = t % H; t /= H; int c = t % C; int b = t / C;
    float d = dist[(size_t)b * HW + yh * W + xw];
    constexpr bool ident = (LVL == 2);
    int ry = ident ? yh : (yh * GW) / H;
    int rx = ident ? xw : (xw * GW) / W;
    float bv = b2f(bsf[((size_t)b * C + c) * PP + ry * GW + rx]);
    out[idx] = x[idx] + fmaxf(bv * d, 0.0f);
}

__global__ __launch_bounds__(256) void k_final_f(
    const float* __restrict__ x0, const float* __restrict__ x1,
    const float* __restrict__ x2, const float* __restrict__ x3,
    const float* __restrict__ x4, const unsigned short* __restrict__ bsf,
    const float* __restrict__ basic, float* __restrict__ out)
{
    int bx = blockIdx.x;
    int tid = threadIdx.x;
    if (bx < 8000) {
        int t0 = bx * 256 + tid;
        #pragma unroll
        for (int k = 0; k < 5; k++)
            final_v4<0>(t0 + k * 2048000, x0, bsf, basic, out);
    } else if (bx < 10000) {
        int t0 = (bx - 8000) * 256 + tid;
        #pragma unroll
        for (int k = 0; k < 5; k++)
            final_v4<1>(t0 + k * 512000, x1, bsf, basic + 160000, out + 40960000ull);
    } else if (bx < 12000) {
        int t0 = (bx - 10000) * 256 + tid;
        #pragma unroll
        for (int k = 0; k < 5; k++)
            final_s<2>(t0 + k * 512000, x2, bsf, basic + 200000, out + 51200000ull);
    } else if (bx < 12500) {
        int t0 = (bx - 12000) * 256 + tid;
        #pragma unroll
        for (int k = 0; k < 5; k++)
            final_s<3>(t0 + k * 128000, x3, bsf, basic + 210000, out + 53760000ull);
    } else {
        int t0 = (bx - 12500) * 256 + tid;
        #pragma unroll
        for (int k = 0; k < 4; k++)
            final_s<4>(t0 + k * 43264, x4, bsf, basic + 212500, out + 54400000ull);
    }
}

// ================= host =================
extern "C" void kernel_launch(void* const* d_in, const int* in_sizes, int n_in,
                              void* d_out, int out_size, void* d_ws, size_t ws_size,
                              hipStream_t stream)
{
    const float* x[5]; for (int i = 0; i < 5; i++) x[i] = (const float*)d_in[i];
    const float* rc_w  = (const float*)d_in[5];
    const float* rc_b  = (const float*)d_in[6];
    const float* g_b   = (const float*)d_in[8];
    const float* th_b  = (const float*)d_in[10];
    const float* ph_b  = (const float*)d_in[12];
    const float* out_b = (const float*)d_in[14];
    float* out = (float*)d_out;

    float* ws    = (float*)d_ws;
    float* ori   = ws + OFF_ORI;
    unsigned short* bsf = (unsigned short*)(ws + OFF_BSF);   // bf16 bsf
    float* zbuf  = ws + OFF_Z;
    float* basic = ws + OFF_BASIC;
    float* rowb  = ws + OFF_ROW;
    float* colb  = ws + OFF_COL;
    float* stats = ws + OFF_STATS;
    float* rowsum = ws + OFF_RSUM;
    unsigned short* u16 = (unsigned short*)(ws + OFF_U16);
    unsigned short* orit = u16 + U_ORIT;
    unsigned short* tht  = u16 + U_THT;
    unsigned short* pht  = u16 + U_PHT;
    unsigned short* gb   = u16 + U_G;
    unsigned short* ytt  = u16 + U_YTT;
    unsigned short* wb   = u16 + U_WB;
    unsigned short* wb_out = wb + 196608;

    // scratch in d_out (fully consumed before k_final_f writes)
    unsigned short* S_all = (unsigned short*)out;            // u16 [4][2560][2560]
    float* part = out + 4 * SPB;                             // fp32 [8][2560][256]

    // 1) pre: rowm + colm + wcvt + ctap + orife + rowsum-zero (one launch)
    k_pre<<<4824, 256, 0, stream>>>(
        x[0], x[1], x[2], x[3], x[4], rc_w,
        (const float*)d_in[9], (const float*)d_in[11],
        (const float*)d_in[7], (const float*)d_in[13],
        wb, ori, zbuf, rowb, colb, rowsum);

    // 2) ori transpose+convert
    k_tcvt<<<dim3(PP / 64, C / 64, B), 256, 0, stream>>>(ori, orit);

    // 3) merged projections th/ph/g (z = b*3 + wsel); g pads zeroed
    k_proj<<<dim3(20, 2, 12), 256, 0, stream>>>(wb, orit, th_b, ph_b, g_b, tht, pht, gb);

    // small per-level chain (independent of attention)
    k_ccomb_f<<<(ZT + 255) / 256, 256, 0, stream>>>(zbuf, rc_b, basic);
    k_stats_f<<<20, 256, 0, stream>>>(rowb, colb, basic, stats);
    k_dist_f<<<(ZT + 255) / 256, 256, 0, stream>>>(basic, rowb, colb, stats);

    // 4) S = tht @ pht^T  (bf16 out, in d_out)
    dim3 gsc(PP / 128, PP / 128, B);
    k_bgemm<false, false, true, false><<<gsc, 256, 0, stream>>>(
        tht, pht, nullptr, nullptr, S_all, C, C, C, PP, CPP, CPP, SPB, 0, 1, 0, nullptr);

    // 5) yt_unnorm = exp(S) @ g^T (exp fused in staging, rowsum via atomics),
    //    split-K x2, fp32 partials
    dim3 gyt(C / 128, PP / 128, B * 2);
    k_bgemm<false, false, false, true><<<gyt, 256, 0, stream>>>(
        S_all, gb, nullptr, nullptr, part, PP / 2, PP, PP, C, SPB, CPP, PS, 0, 2, PP / 2,
        rowsum);

    // 6) reduce + normalize -> ytt [p][c] bf16
    k_ytred<<<(B * CPP / 4 + 255) / 256, 256, 0, stream>>>(part, rowsum, ytt);

    // 7) bsf = out_w @ yt + out_b + ori  (bf16 out)
    dim3 gbsf(PP / 128, C / 128, B);
    k_bgemm<true, true, true, false><<<gbsf, 256, 0, stream>>>(
        wb_out, ytt, out_b, ori, bsf, C, C, C, PP, 0, CPP, CPP, CPP, 1, 0, nullptr);

    // 8) finals (one launch, all levels, 5x/4x batched)
    k_final_f<<<12669, 256, 0, stream>>>(
        x[0], x[1], x[2], x[3], x[4], bsf, basic, out);
}